// Round 11
// baseline (1040.802 us; speedup 1.0000x reference)
//
#include <hip/hip_runtime.h>
#include <cstdint>
#include <cstddef>
#include <cmath>

// DiffusionActiveInference on MI355X (gfx950).
// R17 (resubmit #3; three infra UnresponsiveContainer failures - transport
// died "sending first message", i.e. before kernel content reached the
// container; kernel audited clean for faults/hangs):
// pd1v -> persistent-B streaming kernel. All R12-R15 pd1v variants
// shared pipeline depth K/64 = 4 (no steady state; MfmaUtil 19%). New
// axis: B panel (192 cols x 256 K = 96KB) lives in LDS permanently; A
// streamed in 32-row chunks (16KB, triple-buffered, 48KB) -> depth 32
// with counted vmcnt(4) (chunk waited 2 compute-iters after issue).
// Grid exactly 256 = 16 row-groups x 16 col-panels; same-rg blocks pinned
// to one XCD (A stream L2-shared). Same kg-ascending accumulation order
// and fragment/swizzle layout -> bitwise-identical numerics. Everything
// else byte-identical to R16 (1021us measured).

typedef __bf16 bf16;
typedef __attribute__((ext_vector_type(8))) __bf16 bf16x8;
typedef __attribute__((ext_vector_type(4))) __bf16 bf16x4;
typedef __attribute__((ext_vector_type(4))) float f32x4;

static constexpr int BATCH = 1024, NTRAJ = 16, HORIZON = 5;
static constexpr int MR = NTRAJ * BATCH;  // 16384 GEMM rows
static constexpr float ENT_C = 1.4189385332046727f;  // 0.5*(1+log(2*pi))
static constexpr float SUMDISC = 4.90099501f;        // sum 0.99^t, t=0..4

// ---- async global->LDS, 16B per lane ----------------------------------
__device__ __forceinline__ void gld_lds16(const bf16* g, const bf16* l) {
  typedef __attribute__((address_space(1))) const uint32_t gq_t;
  typedef __attribute__((address_space(3))) uint32_t lq_t;
  gq_t* gp = (gq_t*)(uintptr_t)g;
  lq_t* lp = (lq_t*)(uint32_t)(uintptr_t)l;
  __builtin_amdgcn_global_load_lds(gp, lp, 16, 0, 0);
}

// silu via raw v_rcp_f32: avoids the IEEE div expansion (~10 VALU ops).
__device__ __forceinline__ float silu(float x) {
  return x * __builtin_amdgcn_rcpf(1.f + __expf(-x));
}

#define MFMA16(a, b, c) __builtin_amdgcn_mfma_f32_16x16x32_bf16((a), (b), (c), 0, 0, 0)
#define SBAR() __builtin_amdgcn_s_barrier()
#define SCHED0() __builtin_amdgcn_sched_barrier(0)
#define VMCNT(n) asm volatile("s_waitcnt vmcnt(" #n ")" ::: "memory")
#define LGKMCNT0() asm volatile("s_waitcnt lgkmcnt(0)" ::: "memory")

// ---- generic GEMM: C = maybe_silu(A[M,K](lda) @ Bt[N,K]^T + bias) -----
// dbuf 2-phase 128-tile, counted vmcnt. K = nt*64, nt >= 2.
__global__ __launch_bounds__(256) void gemm128(
    const bf16* __restrict__ A, int lda, int K, const bf16* __restrict__ Bt,
    const float* __restrict__ bias, int act_cols,
    bf16* __restrict__ C1, bf16* __restrict__ C2, int ldc) {
  __shared__ alignas(16) bf16 PA[2][2][128 * 32];
  __shared__ alignas(16) bf16 PB[2][2][128 * 32];
  const int tid = threadIdx.x, wave = tid >> 6, lane = tid & 63;
  const int quad = lane >> 4, l16 = lane & 15;
  const int rowBlk = blockIdx.x * 128, colBlk = blockIdx.y * 128;
  const int wr = wave >> 1, wc = wave & 1;
  const int srow = lane >> 2;
  const int skel = (((lane & 3) ^ ((lane >> 3) & 3)) * 8);
  const int qsw = quad ^ ((l16 >> 1) & 3);

  const bf16* gA0 = A + (size_t)(rowBlk + wave * 32 + srow) * lda + skel;
  const bf16* gA1 = gA0 + (size_t)16 * lda;
  const bf16* gB0 = Bt + (size_t)(colBlk + wave * 32 + srow) * K + skel;
  const bf16* gB1 = gB0 + (size_t)16 * K;

#define STG128(t, b)                                      \
  do {                                                    \
    const int k0_ = (t)*64;                               \
    gld_lds16(gA0 + k0_, &PA[b][0][wave * 1024]);         \
    gld_lds16(gA1 + k0_, &PA[b][0][wave * 1024 + 512]);   \
    gld_lds16(gA0 + k0_ + 32, &PA[b][1][wave * 1024]);    \
    gld_lds16(gA1 + k0_ + 32, &PA[b][1][wave * 1024 + 512]); \
    gld_lds16(gB0 + k0_, &PB[b][0][wave * 1024]);         \
    gld_lds16(gB1 + k0_, &PB[b][0][wave * 1024 + 512]);   \
    gld_lds16(gB0 + k0_ + 32, &PB[b][1][wave * 1024]);    \
    gld_lds16(gB1 + k0_ + 32, &PB[b][1][wave * 1024 + 512]); \
  } while (0)

  f32x4 acc[4][4] = {};
  const int nt = K >> 6;
  STG128(0, 0);
  STG128(1, 1);
  VMCNT(8);
  SBAR();
  SCHED0();
  for (int t = 0; t < nt; ++t) {
    const int b = t & 1;
#pragma unroll
    for (int ks = 0; ks < 2; ++ks) {
      const bf16* aRd = &PA[b][ks][(wr * 64 + l16) * 32 + qsw * 8];
      const bf16* bRd = &PB[b][ks][(wc * 64 + l16) * 32 + qsw * 8];
      bf16x8 af[4], bfr[4];
#pragma unroll
      for (int i = 0; i < 4; ++i) {
        af[i] = *(const bf16x8*)(aRd + i * 16 * 32);
        bfr[i] = *(const bf16x8*)(bRd + i * 16 * 32);
      }
#pragma unroll
      for (int mi = 0; mi < 4; ++mi)
#pragma unroll
        for (int ni = 0; ni < 4; ++ni)
          acc[mi][ni] = MFMA16(bfr[ni], af[mi], acc[mi][ni]);
    }
    if (t == nt - 1) break;
    SBAR();  // all waves done reading buf b
    SCHED0();
    if (t + 2 < nt) {
      STG128(t + 2, b);
      VMCNT(8);
    } else {
      VMCNT(0);
    }
    SBAR();  // buf b^1 ready
    SCHED0();
  }
#undef STG128

  const bool doAct = (colBlk < act_cols);
  bf16* const Cp = doAct ? C1 : C2;
  const int cShift = doAct ? 0 : act_cols;
#pragma unroll
  for (int mi = 0; mi < 4; ++mi) {
    const int row = rowBlk + wr * 64 + mi * 16 + l16;
#pragma unroll
    for (int ni = 0; ni < 4; ++ni) {
      const int col0 = colBlk + wc * 64 + ni * 16 + quad * 4;
      const f32x4 bb = *(const f32x4*)(bias + col0);
      bf16x4 o;
#pragma unroll
      for (int r = 0; r < 4; ++r) {
        float x = acc[mi][ni][r] + bb[r];
        if (doAct) x = silu(x);
        o[r] = (bf16)x;
      }
      *(bf16x4*)(Cp + (size_t)row * ldc + (col0 - cShift)) = o;
    }
  }
}

// ---- per-step trunk, persistent-B streaming: [policy | dyn-z | value] -
// K=256. 256 blocks: xcd=flat&7, idx=flat>>3; rg=xcd*2+(idx&1) (1024-row
// group, same-rg blocks share one XCD's L2 for the A stream), cp=idx>>1
// (192-col panel). B panel 96KB persistent; A 32-row chunks triple-buf.
__global__ __launch_bounds__(512) void gemm_pd1v_ps(
    const bf16* __restrict__ A, const bf16* __restrict__ Bt,
    const float* __restrict__ pdb1, const float* __restrict__ vbiasT,
    bf16* __restrict__ Ha, bf16* __restrict__ Hp, bf16* __restrict__ Hv) {
  __shared__ alignas(16) bf16 Bs[8 * 192 * 32];    // 96KB, persistent
  __shared__ alignas(16) bf16 As[3][8 * 32 * 32];  // 3 x 16KB stream bufs
  const int tid = threadIdx.x, wave = tid >> 6, lane = tid & 63;
  const int quad = lane >> 4, l16 = lane & 15;
  const int wr = wave >> 2, wc = wave & 3;  // 2 (rows) x 4 (cols)
  const int srow = lane >> 2;
  const int skel = (((lane & 3) ^ ((lane >> 3) & 3)) * 8);
  const int qsw = quad ^ ((l16 >> 1) & 3);

  const int flat = blockIdx.x;  // 256
  const int xcd = flat & 7, idx = flat >> 3;
  const int rg = xcd * 2 + (idx & 1);  // 0..15
  const int cp = idx >> 1;             // 0..15
  const int colBase = cp * 192;
  const int row0 = rg * 1024;

  // load B panel once: wave w owns K-group w (32 K), 12 row-subpanels
#pragma unroll
  for (int i = 0; i < 12; ++i)
    gld_lds16(Bt + (size_t)(colBase + i * 16 + srow) * 256 + wave * 32 + skel,
              Bs + (wave * 192 + i * 16) * 32);

#define STG_A(c, bb)                                                        \
  do {                                                                      \
    const bf16* g_ =                                                        \
        A + (size_t)(row0 + (c) * 32 + srow) * 256 + wave * 32 + skel;      \
    bf16* l_ = As[bb] + (wave * 32) * 32;                                   \
    gld_lds16(g_, l_);                                                      \
    gld_lds16(g_ + 16 * 256, l_ + 16 * 32);                                 \
  } while (0)

  STG_A(0, 0);
  STG_A(1, 1);
  STG_A(2, 2);
  VMCNT(4);  // B (12/wave) + A0 landed; A1,A2 in flight
  SBAR();
  SCHED0();

  int b = 0;
  for (int c = 0; c < 32; ++c) {
    f32x4 acc[3] = {};
    const bf16* lA = As[b];
#pragma unroll
    for (int kg = 0; kg < 8; ++kg) {
      const bf16x8 af =
          *(const bf16x8*)(lA + (kg * 32 + wr * 16 + l16) * 32 + qsw * 8);
#pragma unroll
      for (int n = 0; n < 3; ++n) {
        const bf16x8 bfr = *(const bf16x8*)(
            Bs + (kg * 192 + wc * 48 + n * 16 + l16) * 32 + qsw * 8);
        acc[n] = MFMA16(bfr, af, acc[n]);
      }
    }
    SBAR();  // all waves done reading As[b]
    SCHED0();
    if (c + 3 < 32) {
      STG_A(c + 3, b);
      VMCNT(4);  // A(c+1) landed (>=10 queue entries newer than it)
    } else if (c + 2 < 32) {
      VMCNT(2);
    } else if (c + 1 < 32) {
      VMCNT(0);
    }
    SBAR();  // next buf ready
    SCHED0();
    // epilogue for chunk c: register-only inputs; placed after barriers so
    // its stores queue BELOW the next iteration's vmcnt-critical loads.
    const int row = row0 + c * 32 + wr * 16 + l16;
#pragma unroll
    for (int n = 0; n < 3; ++n) {
      const int gcol = colBase + wc * 48 + n * 16 + quad * 4;
      const int seg = gcol >> 10;  // 0 policy(silu), 1 dyn-z, 2 value(silu)
      bf16* const Cp = (seg == 0) ? Ha : (seg == 1) ? Hp : Hv;
      const float* const bp = (seg == 2) ? (vbiasT - 2048) : pdb1;
      const f32x4 bb = *(const f32x4*)(bp + gcol);
      bf16x4 o;
#pragma unroll
      for (int r = 0; r < 4; ++r) {
        float x = acc[n][r] + bb[r];
        if (seg != 1) x = silu(x);
        o[r] = (bf16)x;
      }
      *(bf16x4*)(Cp + (size_t)row * 1024 + (gcol - (seg << 10))) = o;
    }
    b = (b == 2) ? 0 : b + 1;
  }
#undef STG_A
}

// ---- 256x256 8-phase GEMM body (shared by gemm256 and gemm256_dual) ---
template <int NT, int EPI>
__device__ __forceinline__ void gemm256_body(
    const bf16* __restrict__ A, const bf16* __restrict__ Bt, int rowBlk,
    int colBlk, const float* __restrict__ bias, const float* __restrict__ aux,
    bf16* __restrict__ C1, float* __restrict__ efe, float disc,
    bf16 (*sAB)[2][256 * 64]) {
  constexpr int K = NT * 64;
  const int tid = threadIdx.x, wave = tid >> 6, lane = tid & 63;
  const int quad = lane >> 4, l16 = lane & 15;
  const int wr = wave >> 2, wc = wave & 3;  // 2 x 4 wave grid

  const int j8 = lane >> 3;
  const int c16e = ((lane & 7) ^ j8) * 8;  // inverse-swizzled source col
  const bf16* gAs = A + (size_t)(rowBlk + wave * 16 + j8) * K + c16e;
  const bf16* gBs = Bt + (size_t)(colBlk + wave * 16 + j8) * K + c16e;

#define STAGE_A(hh, tt, bb)                                           \
  do {                                                                \
    const bf16* g_ = gAs + (hh) * 128 * K + (tt) * 64;                \
    bf16* l_ = &sAB[(bb)][0][((hh) * 128 + wave * 16) * 64];          \
    gld_lds16(g_, l_);                                                \
    gld_lds16(g_ + 8 * K, l_ + 8 * 64);                               \
  } while (0)
#define STAGE_B(hh, tt, bb)                                           \
  do {                                                                \
    const bf16* g_ = gBs + (hh) * 128 * K + (tt) * 64;                \
    bf16* l_ = &sAB[(bb)][1][((hh) * 128 + wave * 16) * 64];          \
    gld_lds16(g_, l_);                                                \
    gld_lds16(g_ + 8 * K, l_ + 8 * 64);                               \
  } while (0)

  const int k0x = (quad * 8) ^ ((l16 & 7) << 3);
  const int aOff = (wr * 128 + l16) * 64 + k0x;
  const int bOff = (wc * 64 + l16) * 64 + k0x;

  bf16x8 bAf[4][2], bBf[2][2], bB2f[2][2];
  f32x4 acc[8][4] = {};

  // prologue: tile0 fully + tile1 B-halves
  STAGE_A(0, 0, 0);
  STAGE_A(1, 0, 0);
  STAGE_B(0, 0, 0);
  STAGE_B(1, 0, 0);
  STAGE_B(0, 1, 1);
  STAGE_B(1, 1, 1);
  VMCNT(4);
  SBAR();
  SCHED0();

#pragma unroll 2
  for (int t = 0; t < NT; ++t) {
    const int buf = t & 1;
    const bf16* lA = &sAB[buf][0][0];
    const bf16* lB = &sAB[buf][1][0];

    // q0: read A m0-3 + B n0-1; stage A0(t+1); MFMA q0
#pragma unroll
    for (int m = 0; m < 4; ++m)
#pragma unroll
      for (int ks = 0; ks < 2; ++ks)
        bAf[m][ks] = *(const bf16x8*)(lA + ((aOff + m * 1024) ^ (ks << 5)));
#pragma unroll
    for (int n = 0; n < 2; ++n)
#pragma unroll
      for (int ks = 0; ks < 2; ++ks)
        bBf[n][ks] = *(const bf16x8*)(lB + ((bOff + n * 1024) ^ (ks << 5)));
    if (t + 1 < NT) STAGE_A(0, t + 1, buf ^ 1);
    SBAR();
    LGKMCNT0();
    SCHED0();
    __builtin_amdgcn_s_setprio(1);
#pragma unroll
    for (int ks = 0; ks < 2; ++ks)
#pragma unroll
      for (int m = 0; m < 4; ++m)
#pragma unroll
        for (int n = 0; n < 2; ++n)
          acc[m][n] = MFMA16(bBf[n][ks], bAf[m][ks], acc[m][n]);
    __builtin_amdgcn_s_setprio(0);
    SBAR();
    SCHED0();

    // q1: read B n2-3; stage A1(t+1); MFMA m0-3 x n2-3
#pragma unroll
    for (int n = 0; n < 2; ++n)
#pragma unroll
      for (int ks = 0; ks < 2; ++ks)
        bB2f[n][ks] =
            *(const bf16x8*)(lB + ((bOff + (n + 2) * 1024) ^ (ks << 5)));
    if (t + 1 < NT) STAGE_A(1, t + 1, buf ^ 1);
    SBAR();
    LGKMCNT0();
    SCHED0();
    __builtin_amdgcn_s_setprio(1);
#pragma unroll
    for (int ks = 0; ks < 2; ++ks)
#pragma unroll
      for (int m = 0; m < 4; ++m)
#pragma unroll
        for (int n = 0; n < 2; ++n)
          acc[m][n + 2] = MFMA16(bB2f[n][ks], bAf[m][ks], acc[m][n + 2]);
    __builtin_amdgcn_s_setprio(0);
    SBAR();
    SCHED0();

    // q2: read A m4-7; stage B0(t+2); MFMA m4-7 x n2-3
#pragma unroll
    for (int m = 0; m < 4; ++m)
#pragma unroll
      for (int ks = 0; ks < 2; ++ks)
        bAf[m][ks] =
            *(const bf16x8*)(lA + ((aOff + (m + 4) * 1024) ^ (ks << 5)));
    if (t + 2 < NT) STAGE_B(0, t + 2, buf);
    SBAR();
    LGKMCNT0();
    SCHED0();
    __builtin_amdgcn_s_setprio(1);
#pragma unroll
    for (int ks = 0; ks < 2; ++ks)
#pragma unroll
      for (int m = 0; m < 4; ++m)
#pragma unroll
        for (int n = 0; n < 2; ++n)
          acc[m + 4][n + 2] =
              MFMA16(bB2f[n][ks], bAf[m][ks], acc[m + 4][n + 2]);
    __builtin_amdgcn_s_setprio(0);
    SBAR();
    SCHED0();

    // q3: no reads; stage B1(t+2); MFMA m4-7 x n0-1; counted vmcnt
    if (t + 2 < NT) STAGE_B(1, t + 2, buf);
    SBAR();
    SCHED0();
    __builtin_amdgcn_s_setprio(1);
#pragma unroll
    for (int ks = 0; ks < 2; ++ks)
#pragma unroll
      for (int m = 0; m < 4; ++m)
#pragma unroll
        for (int n = 0; n < 2; ++n)
          acc[m + 4][n] = MFMA16(bBf[n][ks], bAf[m][ks], acc[m + 4][n]);
    __builtin_amdgcn_s_setprio(0);
    if (t < NT - 2) {
      VMCNT(4);
    } else {
      VMCNT(0);
    }
    SBAR();
    SCHED0();
  }
#undef STAGE_A
#undef STAGE_B

  if constexpr (EPI == 0) {  // silu(acc + bias) -> C1, ldc=1024
#pragma unroll
    for (int m = 0; m < 8; ++m) {
      const int row = rowBlk + wr * 128 + m * 16 + l16;
#pragma unroll
      for (int n = 0; n < 4; ++n) {
        const int gcol = colBlk + wc * 64 + n * 16 + quad * 4;
        const f32x4 bb = *(const f32x4*)(bias + gcol);
        bf16x4 o;
#pragma unroll
        for (int r = 0; r < 4; ++r) o[r] = (bf16)silu(acc[m][n][r] + bb[r]);
        *(bf16x4*)(C1 + (size_t)row * 1024 + gcol) = o;
      }
    }
  } else {  // EPI == 1: value L2 + vW3 dot -> efe
#pragma unroll
    for (int m = 0; m < 8; ++m) {
      const int row = rowBlk + wr * 128 + m * 16 + l16;
      float p = 0.f;
#pragma unroll
      for (int n = 0; n < 4; ++n) {
        const int gcol = colBlk + wc * 64 + n * 16 + quad * 4;
        const f32x4 bb = *(const f32x4*)(bias + gcol);
        const f32x4 w3 = *(const f32x4*)(aux + gcol);
#pragma unroll
        for (int r = 0; r < 4; ++r) p += silu(acc[m][n][r] + bb[r]) * w3[r];
      }
      p += __shfl_xor(p, 16);
      p += __shfl_xor(p, 32);
      if (quad == 0) atomicAdd(efe + row, disc * p);
    }
  }
}

template <int NT, int EPI>
__global__ __launch_bounds__(512, 2) void gemm256(
    const bf16* __restrict__ A, const bf16* __restrict__ Bt, int nCol,
    const float* __restrict__ bias, const float* __restrict__ aux,
    bf16* __restrict__ C1, float* __restrict__ efe, float disc) {
  static_assert(NT >= 2, "need at least 2 K-tiles");
  __shared__ alignas(16) bf16 sAB[2][2][256 * 64];
  const int nwg = gridDim.x, flat = blockIdx.x;
  const int lid = (flat & 7) * (nwg >> 3) + (flat >> 3);
  const int rowBlk = (lid / nCol) * 256, colBlk = (lid % nCol) * 256;
  gemm256_body<NT, EPI>(A, Bt, rowBlk, colBlk, bias, aux, C1, efe, disc, sAB);
}

// fused {policy-L2 (EPI0), value-L2+dot (EPI1)}: grid 256, TEMPORAL.
template <int NT>
__global__ __launch_bounds__(512, 2) void gemm256_dual(
    const bf16* __restrict__ A0, const bf16* __restrict__ Bt0,
    const float* __restrict__ bias0, bf16* __restrict__ C0,
    const bf16* __restrict__ A1, const bf16* __restrict__ Bt1,
    const float* __restrict__ bias1, const float* __restrict__ aux1,
    float* __restrict__ efe, float disc) {
  __shared__ alignas(16) bf16 sAB[2][2][256 * 64];
  const int flat = blockIdx.x;  // 256 blocks
  const int seq = (flat & 7) * 32 + (flat >> 3);  // 0..255, XCD-chunked
  const int rowBlk = (seq >> 2) * 256, colBlk = (seq & 3) * 256;
  gemm256_body<NT, 0>(A0, Bt0, rowBlk, colBlk, bias0, nullptr, C0, nullptr,
                      0.f, sAB);
  gemm256_body<NT, 1>(A1, Bt1, rowBlk, colBlk, bias1, aux1, nullptr, efe,
                      disc, sAB);
}

// ---- dynamics L3 + z_next + KL partials fused -------------------------
// dbuf + counted vmcnt (6 loads/thread per stage), K=1024 (nt=16).
__global__ __launch_bounds__(256) void gemm_dyn3(
    const bf16* __restrict__ A, const bf16* __restrict__ Bt,
    const float* __restrict__ db3, float* __restrict__ Zf,
    bf16* __restrict__ Zb, float* __restrict__ s_n, float* __restrict__ s_c) {
  __shared__ alignas(16) bf16 PA[2][2][64 * 32];
  __shared__ alignas(16) bf16 PB[2][2][128 * 32];
  const int tid = threadIdx.x, wave = tid >> 6, lane = tid & 63;
  const int quad = lane >> 4, l16 = lane & 15;
  const int rowBlk = blockIdx.x * 64, colBlk = blockIdx.y * 128;
  const int srow = lane >> 2;
  const int skel = (((lane & 3) ^ ((lane >> 3) & 3)) * 8);
  const int qsw = quad ^ ((l16 >> 1) & 3);

  const bf16* gA = A + (size_t)(rowBlk + wave * 16 + srow) * 1024 + skel;
  const bf16* gB0 = Bt + (size_t)(colBlk + wave * 32 + srow) * 1024 + skel;
  const bf16* gB1 = gB0 + (size_t)16 * 1024;

#define STGD(t, b)                                        \
  do {                                                    \
    const int k0_ = (t)*64;                               \
    gld_lds16(gA + k0_, &PA[b][0][wave * 512]);           \
    gld_lds16(gA + k0_ + 32, &PA[b][1][wave * 512]);      \
    gld_lds16(gB0 + k0_, &PB[b][0][wave * 1024]);         \
    gld_lds16(gB1 + k0_, &PB[b][0][wave * 1024 + 512]);   \
    gld_lds16(gB0 + k0_ + 32, &PB[b][1][wave * 1024]);    \
    gld_lds16(gB1 + k0_ + 32, &PB[b][1][wave * 1024 + 512]); \
  } while (0)

  f32x4 acc[8] = {};
  STGD(0, 0);
  STGD(1, 1);
  VMCNT(6);
  SBAR();
  SCHED0();
#pragma unroll 2
  for (int t = 0; t < 16; ++t) {
    const int b = t & 1;
#pragma unroll
    for (int ks = 0; ks < 2; ++ks) {
      const bf16* aRd = &PA[b][ks][(wave * 16 + l16) * 32 + qsw * 8];
      const bf16* bRd = &PB[b][ks][l16 * 32 + qsw * 8];
      const bf16x8 af = *(const bf16x8*)aRd;
#pragma unroll
      for (int ni = 0; ni < 8; ++ni) {
        const bf16x8 bfr = *(const bf16x8*)(bRd + ni * 16 * 32);
        acc[ni] = MFMA16(bfr, af, acc[ni]);
      }
    }
    if (t == 15) break;
    SBAR();
    SCHED0();
    if (t < 14) {
      STGD(t + 2, b);
      VMCNT(6);
    } else {
      VMCNT(0);
    }
    SBAR();
    SCHED0();
  }
#undef STGD

  const int row = rowBlk + wave * 16 + l16;
  float pn = 0.f, pc = 0.f;
#pragma unroll
  for (int ni = 0; ni < 8; ++ni) {
    const int col0 = colBlk + ni * 16 + quad * 4;
    const f32x4 b4 = *(const f32x4*)(db3 + col0);
    float* zp = Zf + (size_t)row * 256 + col0;
    const f32x4 z = *(const f32x4*)zp;
    f32x4 zn;
    bf16x4 o;
#pragma unroll
    for (int r = 0; r < 4; ++r) {
      zn[r] = z[r] + acc[ni][r] + b4[r];
      pn += zn[r] * zn[r];
      pc += z[r] * zn[r];
      o[r] = (bf16)zn[r];
    }
    *(f32x4*)zp = zn;
    *(bf16x4*)(Zb + (size_t)row * 256 + col0) = o;
  }
  pn += __shfl_xor(pn, 16);
  pn += __shfl_xor(pn, 32);
  pc += __shfl_xor(pc, 16);
  pc += __shfl_xor(pc, 32);
  if (quad == 0) {
    atomicAdd(s_n + row, pn);
    atomicAdd(s_c + row, pc);
  }
}

// ---- batched KL epilogue: all 5 steps at once -------------------------
__global__ void kl_batch(const float* __restrict__ sz0,
                         const float* __restrict__ snAll,
                         const float* __restrict__ scAll,
                         float* __restrict__ efe) {
  const int m = blockIdx.x * 256 + threadIdx.x;
  float sz = sz0[m];
  float disc = 1.f, acc = 0.f;
  for (int t = 0; t < HORIZON; ++t) {
    const float sn = snAll[t * MR + m], sc = scAll[t * MR + m];
    const float nz = sqrtf(sz) + 1e-8f, nn = sqrtf(sn) + 1e-8f;
    const float kl =
        0.5f * (sz / (nz * nz) + sn / (nn * nn) - 2.f * sc / (nz * nn));
    acc += disc * log1pf(fmaxf(kl, 0.f));
    sz = sn;
    disc *= 0.99f;
  }
  efe[m] += acc;
}

// ---- heads4: split-K heads + dynamics-L1 completion -------------------
// Per-wave panels (wave owns K-quarter) -> NO barriers in k-loop; per-wave
// dbuf + counted VMCNT(5) keeps one tile in flight while computing.
__global__ __launch_bounds__(256) void heads4(
    const bf16* __restrict__ H, const bf16* __restrict__ Wt,
    const float* __restrict__ pbm, const float* __restrict__ pbs,
    const float* __restrict__ noise, const bf16* __restrict__ preD,
    const bf16* __restrict__ dW1at, bf16* __restrict__ Hd,
    float* __restrict__ efe, int t, float disc, int rmask) {
  __shared__ alignas(16) bf16 As[2][4 * 16 * 32];
  __shared__ alignas(16) bf16 Bs[2][4 * 64 * 32];  // Bs[0] aliased as f32 red
  __shared__ alignas(16) bf16 LAct[16 * 32];
  const int tid = threadIdx.x, wave = tid >> 6, lane = tid & 63;
  const int quad = lane >> 4, l16 = lane & 15;
  const int rowBlk = blockIdx.x * 16;
  const int srow = lane >> 2;
  const int skel = (((lane & 3) ^ ((lane >> 3) & 3)) * 8);
  const int qsw = quad ^ ((l16 >> 1) & 3);
  const int kw = wave * 256;

  const bf16* gA = H + (size_t)((rowBlk + srow) & rmask) * 1024 + kw + skel;

#define STGH(kt, b)                                                         \
  do {                                                                      \
    gld_lds16(gA + (kt) * 32, &As[b][wave * 512]);                          \
    _Pragma("unroll") for (int j = 0; j < 4; ++j) gld_lds16(                \
        Wt + (size_t)(j * 16 + srow) * 1024 + kw + (kt) * 32 + skel,        \
        &Bs[b][wave * 2048 + j * 512]);                                     \
  } while (0)

  f32x4 acc[4] = {};
  STGH(0, 0);
  STGH(1, 1);  // 10 loads in flight
#pragma unroll
  for (int kt = 0; kt < 8; ++kt) {
    const int b = kt & 1;
    if (kt < 7) {
      VMCNT(5);  // tile kt landed; tile kt+1 stays in flight
    } else {
      VMCNT(0);
    }
    SCHED0();
    const bf16x8 af =
        *(const bf16x8*)(&As[b][wave * 512] + l16 * 32 + qsw * 8);
#pragma unroll
    for (int ni = 0; ni < 4; ++ni) {
      const bf16x8 bfr =
          *(const bf16x8*)(&Bs[b][wave * 2048] + (ni * 16 + l16) * 32 + qsw * 8);
      acc[ni] = MFMA16(bfr, af, acc[ni]);
    }
    SCHED0();  // pin: ds_reads/MFMA above, restage below
    if (kt < 6) {
      LGKMCNT0();  // ds_reads of buf b fully retired before overwrite
      STGH(kt + 2, b);
    }
  }
#undef STGH

  // cross-wave reduction: partials through Bs[0]-aliased f32 scratch
  float* red = (float*)Bs;  // wave w's slice aliases its OWN Bs[0] panel
#pragma unroll
  for (int ni = 0; ni < 4; ++ni)
    *(f32x4*)(red + wave * 1024 + ni * 256 + lane * 4) = acc[ni];
  __syncthreads();
#pragma unroll
  for (int ni = 0; ni < 4; ++ni) {
    f32x4 s = *(const f32x4*)(red + ni * 256 + lane * 4);
#pragma unroll
    for (int w2 = 1; w2 < 4; ++w2) {
      const f32x4 p = *(const f32x4*)(red + w2 * 1024 + ni * 256 + lane * 4);
#pragma unroll
      for (int r = 0; r < 4; ++r) s[r] += p[r];
    }
    acc[ni] = s;
  }

  // action + entropy (computed redundantly by all waves; wave0 writes)
  const int row = rowBlk + l16;
  const int n = row >> 10, b2 = row & 1023;
  float ent = 0.f;
#pragma unroll
  for (int ni = 0; ni < 2; ++ni) {
    const int col0 = ni * 16 + quad * 4;
    const f32x4 bm4 = *(const f32x4*)(pbm + col0);
    const f32x4 bs4 = *(const f32x4*)(pbs + col0);
    const f32x4 ep4 =
        *(const f32x4*)(noise + (((size_t)(n * 5 + t) * 1024 + b2) * 32 + col0));
    bf16x4 o;
#pragma unroll
    for (int r = 0; r < 4; ++r) {
      const float mean = acc[ni][r] + bm4[r];
      float ls = acc[ni + 2][r] + bs4[r];
      ls = fminf(fmaxf(ls, -5.f), 2.f);
      o[r] = (bf16)(mean + __expf(ls) * ep4[r]);
      ent += ENT_C + ls;
    }
    if (wave == 0) *(bf16x4*)(LAct + l16 * 32 + col0) = o;
  }
  ent += __shfl_xor(ent, 16);
  ent += __shfl_xor(ent, 32);
  if (wave == 0 && quad == 0) efe[row] += disc * (-0.1f) * ent;
  __syncthreads();  // LAct ready

  // rank-32 completion: wave w handles col-tiles [w*16, w*16+16)
  const int prow = row & rmask;
  const bf16x8 af2 = *(const bf16x8*)(LAct + l16 * 32 + quad * 8);
#pragma unroll 4
  for (int ci = 0; ci < 16; ++ci) {
    const int ct = wave * 16 + ci;
    const bf16x8 wf =
        *(const bf16x8*)(dW1at + (size_t)(ct * 16 + l16) * 32 + quad * 8);
    f32x4 a = {};
    a = MFMA16(wf, af2, a);
    const int col0 = ct * 16 + quad * 4;
    const bf16x4 pd = *(const bf16x4*)(preD + (size_t)prow * 1024 + col0);
    bf16x4 o;
#pragma unroll
    for (int r = 0; r < 4; ++r) o[r] = (bf16)silu(a[r] + (float)pd[r]);
    *(bf16x4*)(Hd + (size_t)row * 1024 + col0) = o;
  }
}

// ---- unified prep: coalesced tiled transposes + vbias + init ----------
__global__ __launch_bounds__(256) void prep_tr(
    const float* __restrict__ pW1, const float* __restrict__ dW1,
    const float* __restrict__ vW1, const float* __restrict__ pW2,
    const float* __restrict__ dW2, const float* __restrict__ dW3,
    const float* __restrict__ vW2, const float* __restrict__ pWm,
    const float* __restrict__ pWs, const float* __restrict__ pb1,
    const float* __restrict__ db1, const float* __restrict__ vb1,
    const float* __restrict__ latent, bf16* __restrict__ pdW1vt,
    bf16* __restrict__ pW2t, bf16* __restrict__ pHt,
    bf16* __restrict__ dW1at, bf16* __restrict__ dW2t,
    bf16* __restrict__ dW3t, bf16* __restrict__ vW2t,
    float* __restrict__ pdb1, float* __restrict__ vbias,
    float* __restrict__ Zf, bf16* __restrict__ Zb0, float* __restrict__ efe,
    float* __restrict__ sz0, float* __restrict__ snAll,
    float* __restrict__ scAll) {
  int bid = blockIdx.x;
  if (bid == 1072) {  // pdb1
    for (int i = threadIdx.x; i < 2048; i += 256)
      pdb1[i] = (i < 1024) ? pb1[i] : db1[i - 1024];
    return;
  }
  if (bid >= 1073 && bid < 1093) {  // vbias
    const int idx = (bid - 1073) * 256 + threadIdx.x;  // < 5120
    const int t = idx >> 10, j = idx & 1023;
    float s = vb1[j];
    const float lt = (float)t;
    for (int i = 0; i < 64; ++i) {
      const float f = expf(-9.210340371976184f * (float)i / 64.f);
      const float ang = lt * f;
      s += sinf(ang) * vW1[(size_t)(256 + i) * 1024 + j];
      s += cosf(ang) * vW1[(size_t)(256 + 64 + i) * 1024 + j];
    }
    vbias[idx] = s;
    return;
  }
  if (bid >= 1093) {  // init: 4 rows/block, wave per row
    const int wave = threadIdx.x >> 6, lane = threadIdx.x & 63;
    const int row = (bid - 1093) * 4 + wave;
    const f32x4 z = *(const f32x4*)(latent + (size_t)(row & 1023) * 256 + lane * 4);
    *(f32x4*)(Zf + (size_t)row * 256 + lane * 4) = z;
    if (row < 1024) {
      bf16x4 o = {(bf16)z[0], (bf16)z[1], (bf16)z[2], (bf16)z[3]};
      *(bf16x4*)(Zb0 + (size_t)row * 256 + lane * 4) = o;
    }
    float s = z[0] * z[0] + z[1] * z[1] + z[2] * z[2] + z[3] * z[3];
#pragma unroll
    for (int m = 1; m < 64; m <<= 1) s += __shfl_xor(s, m);
    if (lane == 0) {
      sz0[row] = s;
      efe[row] = 0.f;
    }
    if (lane < HORIZON) {
      snAll[lane * MR + row] = 0.f;
      scAll[lane * MR + row] = 0.f;
    }
    return;
  }
  // ---- tiled transpose segments ----
  const float* in;
  bf16* out;
  int K, N, ldin, ro = 0;
  if (bid < 64) { in = pW1; out = pdW1vt; K = 256; N = 1024; ldin = 1024; }
  else if (bid < 128) { bid -= 64; in = dW1; out = pdW1vt + 1024 * 256; K = 256; N = 1024; ldin = 1024; }
  else if (bid < 192) { bid -= 128; in = vW1; out = pdW1vt + 2048 * 256; K = 256; N = 1024; ldin = 1024; }
  else if (bid < 448) { bid -= 192; in = pW2; out = pW2t; K = 1024; N = 1024; ldin = 1024; }
  else if (bid < 704) { bid -= 448; in = dW2; out = dW2t; K = 1024; N = 1024; ldin = 1024; }
  else if (bid < 960) { bid -= 704; in = vW2; out = vW2t; K = 1024; N = 1024; ldin = 1024; }
  else if (bid < 1024) { bid -= 960; in = dW3; out = dW3t; K = 1024; N = 256; ldin = 256; }
  else if (bid < 1040) { bid -= 1024; in = dW1; out = dW1at; K = 32; N = 1024; ldin = 1024; ro = 256; }
  else if (bid < 1056) { bid -= 1040; in = pWm; out = pHt; K = 1024; N = 32; ldin = 32; }
  else { bid -= 1056; in = pWs; out = pHt + 32 * 1024; K = 1024; N = 32; ldin = 32; }

  const int ktiles = (K + 63) >> 6;
  const int k0 = (bid % ktiles) * 64, n0 = (bid / ktiles) * 64;
  __shared__ float tile[64][65];
  const int tx = threadIdx.x & 63, ty = threadIdx.x >> 6;
#pragma unroll
  for (int i = 0; i < 16; ++i) {
    const int k = k0 + ty + i * 4;
    if (k < K && n0 + tx < N)
      tile[ty + i * 4][tx] = in[(size_t)(ro + k) * ldin + n0 + tx];
  }
  __syncthreads();
#pragma unroll
  for (int i = 0; i < 16; ++i) {
    const int n = n0 + ty + i * 4;
    if (n < N && k0 + tx < K)
      out[(size_t)n * K + k0 + tx] = (bf16)tile[tx][ty + i * 4];
  }
}

__global__ void finalize(const float* __restrict__ efe,
                         const float* __restrict__ vb3,
                         float* __restrict__ out) {
  const int b = blockIdx.x * 256 + threadIdx.x;  // 1024
  float s = 0.f;
#pragma unroll
  for (int n = 0; n < 16; ++n) s += efe[n * 1024 + b];
  out[b] = s * (1.f / 16.f) + SUMDISC * vb3[0];
}

extern "C" void kernel_launch(void* const* d_in, const int* in_sizes, int n_in,
                              void* d_out, int out_size, void* d_ws,
                              size_t ws_size, hipStream_t stream) {
  const float* latent = (const float*)d_in[0];
  const float* noise = (const float*)d_in[1];
  const float* pW1 = (const float*)d_in[2];
  const float* pb1 = (const float*)d_in[3];
  const float* pW2 = (const float*)d_in[4];
  const float* pb2 = (const float*)d_in[5];
  const float* pWm = (const float*)d_in[6];
  const float* pbm = (const float*)d_in[7];
  const float* pWs = (const float*)d_in[8];
  const float* pbs = (const float*)d_in[9];
  const float* dW1 = (const float*)d_in[10];
  const float* db1 = (const float*)d_in[11];
  const float* dW2 = (const float*)d_in[12];
  const float* db2 = (const float*)d_in[13];
  const float* dW3 = (const float*)d_in[14];
  const float* db3 = (const float*)d_in[15];
  const float* vW1 = (const float*)d_in[16];
  const float* vb1 = (const float*)d_in[17];
  const float* vW2 = (const float*)d_in[18];
  const float* vb2 = (const float*)d_in[19];
  const float* vW3 = (const float*)d_in[20];
  const float* vb3 = (const float*)d_in[21];

  char* w = (char*)d_ws;
  size_t off = 0;
  auto take = [&](size_t bytes) -> void* {
    void* p = (void*)(w + off);
    off = (off + bytes + 255) & ~(size_t)255;
    return p;
  };
  bf16* pdW1vt = (bf16*)take(3072ull * 256 * 2);  // [pW1|dW1z|vW1]^T
  float* pdb1 = (float*)take(2048ull * 4);
  bf16* pW2t = (bf16*)take(1024ull * 1024 * 2);
  bf16* pHt = (bf16*)take(64ull * 1024 * 2);
  bf16* dW1at = (bf16*)take(1024ull * 32 * 2);
  bf16* dW2t = (bf16*)take(1024ull * 1024 * 2);
  bf16* dW3t = (bf16*)take(256ull * 1024 * 2);
  bf16* vW2t = (bf16*)take(1024ull * 1024 * 2);
  float* vbias = (float*)take(5ull * 1024 * 4);
  bf16* Zb0 = (bf16*)take(1024ull * 256 * 2);      // z0 bf16, shared rows
  bf16* Zb = (bf16*)take((size_t)MR * 256 * 2);    // z_t bf16 (single buf)
  float* Zf = (float*)take((size_t)MR * 256 * 4);  // fp32 master z
  float* efe = (float*)take((size_t)MR * 4);
  float* sz0 = (float*)take((size_t)MR * 4);
  float* snAll = (float*)take(5ull * MR * 4);
  float* scAll = (float*)take(5ull * MR * 4);
  bf16* Ha = (bf16*)take((size_t)MR * 1024 * 2);
  bf16* Hc = (bf16*)take((size_t)MR * 1024 * 2);
  bf16* Hp = (bf16*)take((size_t)MR * 1024 * 2);
  bf16* Hv = (bf16*)take((size_t)MR * 1024 * 2);
  bf16* vW1t = pdW1vt + (size_t)2048 * 256;  // value-L1 weights (tail step)

  const dim3 blk(256), blk2(512);
  const int BIG = 1 << 30;
  // prep_tr: 1072 transpose tiles + pdb1 + 20 vbias + 4096 init blocks
  prep_tr<<<dim3(1093 + MR / 4), blk, 0, stream>>>(
      pW1, dW1, vW1, pW2, dW2, dW3, vW2, pWm, pWs, pb1, db1, vb1, latent,
      pdW1vt, pW2t, pHt, dW1at, dW2t, dW3t, vW2t, pdb1, vbias, Zf, Zb0, efe,
      sz0, snAll, scAll);

  float disc = 1.f, dprev = 1.f;
  for (int s = 0; s < HORIZON; ++s) {
    const int rmask = (s == 0) ? 1023 : 0x7FFFFFFF;
    if (s == 0) {
      // [policy L1 | dyn L1z] only: M=1024 (shared latent), N=2048
      gemm128<<<dim3(8, 16), blk, 0, stream>>>(Zb0, 256, 256, pdW1vt, pdb1,
                                               1024, Ha, Hp, 1024);
      // policy L2 at M=1024
      gemm128<<<dim3(8, 8), blk, 0, stream>>>(Ha, 1024, 1024, pW2t, pb2, BIG,
                                              Hc, Hc, 1024);
    } else {
      // trunk + value-L1 for pragmatic(s-1) on z_s: N=3072, K=256
      // persistent-B streaming, grid 256, pipeline depth 32
      gemm_pd1v_ps<<<dim3(256), blk2, 0, stream>>>(
          Zb, pdW1vt, pdb1, vbias + (s - 1) * 1024, Ha, Hp, Hv);
      // fused {policy L2 -> Hc} then {value L2 + vW3 dot -> efe}, grid 256
      gemm256_dual<16><<<dim3(256), blk2, 0, stream>>>(
          Ha, pW2t, pb2, Hc, Hv, vW2t, vb2, vW3, efe, dprev);
    }
    // heads + dyn-L1 completion: Hc,Hp (masked rows) -> action/ent, Hd -> Ha
    heads4<<<dim3(MR / 16), blk, 0, stream>>>(Hc, pHt, pbm, pbs, noise, Hp,
                                              dW1at, Ha, efe, s, disc, rmask);
    // dynamics L2: Ha -> Hc (8-phase 256-tile)
    gemm256<16, 0><<<dim3(256), blk2, 0, stream>>>(Ha, dW2t, 4, db2, nullptr,
                                                   Hc, nullptr, 0.f);
    // dynamics L3 fused with z_next / KL partials; writes Zb = z_{s+1}
    gemm_dyn3<<<dim3(MR / 64, 2), blk, 0, stream>>>(
        Hc, dW3t, db3, Zf, Zb, snAll + (size_t)s * MR, scAll + (size_t)s * MR);
    dprev = disc;
    disc *= 0.99f;
  }

  kl_batch<<<dim3(MR / 256), blk, 0, stream>>>(sz0, snAll, scAll, efe);

  // final pragmatic(4) on z_5: value L1 (dbuf 2-phase, K=256) then L2+dot
  gemm128<<<dim3(128, 8), blk, 0, stream>>>(Zb, 256, 256, vW1t,
                                            vbias + 4 * 1024, BIG, Hv, Hv,
                                            1024);
  gemm256<16, 1><<<dim3(256), blk2, 0, stream>>>(Hv, vW2t, 4, vb2, vW3,
                                                 nullptr, efe, dprev);
  finalize<<<dim3(4), blk, 0, stream>>>(efe, vb3, (float*)d_out);
}

// Round 12
// 1033.592 us; speedup vs baseline: 1.0070x; 1.0070x over previous
//
#include <hip/hip_runtime.h>
#include <cstdint>
#include <cstddef>
#include <cmath>

// DiffusionActiveInference on MI355X (gfx950).
// R18: (1) pd1v CLOSED: persistent-B (R17, 59.5us implied) lost to
// sbuf128 (54.6) like dbuf/sbuf256/8phase before it -> revert trunk to
// the R16 sbuf128 gemm_pd1v permanently. (2) gemm_dyn3 col-fusion: one
// block now does 64 rows x ALL 256 cols (acc[16], B 256x64 staged by 4
// waves, 80KB LDS, grid 256 = 1 block/CU single round). Hc (33.5MB,
// borderline vs 32MB L2) read ONCE instead of twice; s_n/s_c atomics ->
// plain stores. Same dbuf + counted VMCNT(10) structure. Everything else
// byte-identical to R16 (1021us measured).

typedef __bf16 bf16;
typedef __attribute__((ext_vector_type(8))) __bf16 bf16x8;
typedef __attribute__((ext_vector_type(4))) __bf16 bf16x4;
typedef __attribute__((ext_vector_type(4))) float f32x4;

static constexpr int BATCH = 1024, NTRAJ = 16, HORIZON = 5;
static constexpr int MR = NTRAJ * BATCH;  // 16384 GEMM rows
static constexpr float ENT_C = 1.4189385332046727f;  // 0.5*(1+log(2*pi))
static constexpr float SUMDISC = 4.90099501f;        // sum 0.99^t, t=0..4

// ---- async global->LDS, 16B per lane ----------------------------------
__device__ __forceinline__ void gld_lds16(const bf16* g, const bf16* l) {
  typedef __attribute__((address_space(1))) const uint32_t gq_t;
  typedef __attribute__((address_space(3))) uint32_t lq_t;
  gq_t* gp = (gq_t*)(uintptr_t)g;
  lq_t* lp = (lq_t*)(uint32_t)(uintptr_t)l;
  __builtin_amdgcn_global_load_lds(gp, lp, 16, 0, 0);
}

// silu via raw v_rcp_f32: avoids the IEEE div expansion (~10 VALU ops).
__device__ __forceinline__ float silu(float x) {
  return x * __builtin_amdgcn_rcpf(1.f + __expf(-x));
}

#define MFMA16(a, b, c) __builtin_amdgcn_mfma_f32_16x16x32_bf16((a), (b), (c), 0, 0, 0)
#define SBAR() __builtin_amdgcn_s_barrier()
#define SCHED0() __builtin_amdgcn_sched_barrier(0)
#define VMCNT(n) asm volatile("s_waitcnt vmcnt(" #n ")" ::: "memory")
#define LGKMCNT0() asm volatile("s_waitcnt lgkmcnt(0)" ::: "memory")

// ---- generic GEMM: C = maybe_silu(A[M,K](lda) @ Bt[N,K]^T + bias) -----
// dbuf 2-phase 128-tile, counted vmcnt. K = nt*64, nt >= 2.
__global__ __launch_bounds__(256) void gemm128(
    const bf16* __restrict__ A, int lda, int K, const bf16* __restrict__ Bt,
    const float* __restrict__ bias, int act_cols,
    bf16* __restrict__ C1, bf16* __restrict__ C2, int ldc) {
  __shared__ alignas(16) bf16 PA[2][2][128 * 32];
  __shared__ alignas(16) bf16 PB[2][2][128 * 32];
  const int tid = threadIdx.x, wave = tid >> 6, lane = tid & 63;
  const int quad = lane >> 4, l16 = lane & 15;
  const int rowBlk = blockIdx.x * 128, colBlk = blockIdx.y * 128;
  const int wr = wave >> 1, wc = wave & 1;
  const int srow = lane >> 2;
  const int skel = (((lane & 3) ^ ((lane >> 3) & 3)) * 8);
  const int qsw = quad ^ ((l16 >> 1) & 3);

  const bf16* gA0 = A + (size_t)(rowBlk + wave * 32 + srow) * lda + skel;
  const bf16* gA1 = gA0 + (size_t)16 * lda;
  const bf16* gB0 = Bt + (size_t)(colBlk + wave * 32 + srow) * K + skel;
  const bf16* gB1 = gB0 + (size_t)16 * K;

#define STG128(t, b)                                      \
  do {                                                    \
    const int k0_ = (t)*64;                               \
    gld_lds16(gA0 + k0_, &PA[b][0][wave * 1024]);         \
    gld_lds16(gA1 + k0_, &PA[b][0][wave * 1024 + 512]);   \
    gld_lds16(gA0 + k0_ + 32, &PA[b][1][wave * 1024]);    \
    gld_lds16(gA1 + k0_ + 32, &PA[b][1][wave * 1024 + 512]); \
    gld_lds16(gB0 + k0_, &PB[b][0][wave * 1024]);         \
    gld_lds16(gB1 + k0_, &PB[b][0][wave * 1024 + 512]);   \
    gld_lds16(gB0 + k0_ + 32, &PB[b][1][wave * 1024]);    \
    gld_lds16(gB1 + k0_ + 32, &PB[b][1][wave * 1024 + 512]); \
  } while (0)

  f32x4 acc[4][4] = {};
  const int nt = K >> 6;
  STG128(0, 0);
  STG128(1, 1);
  VMCNT(8);
  SBAR();
  SCHED0();
  for (int t = 0; t < nt; ++t) {
    const int b = t & 1;
#pragma unroll
    for (int ks = 0; ks < 2; ++ks) {
      const bf16* aRd = &PA[b][ks][(wr * 64 + l16) * 32 + qsw * 8];
      const bf16* bRd = &PB[b][ks][(wc * 64 + l16) * 32 + qsw * 8];
      bf16x8 af[4], bfr[4];
#pragma unroll
      for (int i = 0; i < 4; ++i) {
        af[i] = *(const bf16x8*)(aRd + i * 16 * 32);
        bfr[i] = *(const bf16x8*)(bRd + i * 16 * 32);
      }
#pragma unroll
      for (int mi = 0; mi < 4; ++mi)
#pragma unroll
        for (int ni = 0; ni < 4; ++ni)
          acc[mi][ni] = MFMA16(bfr[ni], af[mi], acc[mi][ni]);
    }
    if (t == nt - 1) break;
    SBAR();  // all waves done reading buf b
    SCHED0();
    if (t + 2 < nt) {
      STG128(t + 2, b);
      VMCNT(8);
    } else {
      VMCNT(0);
    }
    SBAR();  // buf b^1 ready
    SCHED0();
  }
#undef STG128

  const bool doAct = (colBlk < act_cols);
  bf16* const Cp = doAct ? C1 : C2;
  const int cShift = doAct ? 0 : act_cols;
#pragma unroll
  for (int mi = 0; mi < 4; ++mi) {
    const int row = rowBlk + wr * 64 + mi * 16 + l16;
#pragma unroll
    for (int ni = 0; ni < 4; ++ni) {
      const int col0 = colBlk + wc * 64 + ni * 16 + quad * 4;
      const f32x4 bb = *(const f32x4*)(bias + col0);
      bf16x4 o;
#pragma unroll
      for (int r = 0; r < 4; ++r) {
        float x = acc[mi][ni][r] + bb[r];
        if (doAct) x = silu(x);
        o[r] = (bf16)x;
      }
      *(bf16x4*)(Cp + (size_t)row * ldc + (col0 - cShift)) = o;
    }
  }
}

// ---- per-step trunk: [policy-L1 | dyn-L1z | value-L1] in one GEMM -----
// K=256, N=3072, grid (128,24) = 3072 blocks, single-buf 32KB (5/CU).
// FINAL: sbuf128 beat dbuf128/sbuf256/8phase/persistent-B (R12-R17).
__global__ __launch_bounds__(256) void gemm_pd1v(
    const bf16* __restrict__ A, const bf16* __restrict__ Bt,
    const float* __restrict__ pdb1, const float* __restrict__ vbiasT,
    bf16* __restrict__ Ha, bf16* __restrict__ Hp, bf16* __restrict__ Hv) {
  __shared__ alignas(16) bf16 As0[128 * 32], As1[128 * 32];
  __shared__ alignas(16) bf16 Bs0[128 * 32], Bs1[128 * 32];
  const int tid = threadIdx.x, wave = tid >> 6, lane = tid & 63;
  const int quad = lane >> 4, l16 = lane & 15;
  const int rowBlk = blockIdx.x * 128, colBlk = blockIdx.y * 128;
  const int wr = wave >> 1, wc = wave & 1;
  const int srow = lane >> 2;
  const int skel = (((lane & 3) ^ ((lane >> 3) & 3)) * 8);
  const int qsw = quad ^ ((l16 >> 1) & 3);

  const bf16* gA0 = A + (size_t)(rowBlk + wave * 32 + srow) * 256 + skel;
  const bf16* gA1 = gA0 + (size_t)16 * 256;
  const bf16* gB0 = Bt + (size_t)(colBlk + wave * 32 + srow) * 256 + skel;
  const bf16* gB1 = gB0 + (size_t)16 * 256;
  bf16* const lA0 = As0 + wave * 32 * 32;
  bf16* const lA0b = As0 + (wave * 32 + 16) * 32;
  bf16* const lA1 = As1 + wave * 32 * 32;
  bf16* const lA1b = As1 + (wave * 32 + 16) * 32;
  bf16* const lB0 = Bs0 + wave * 32 * 32;
  bf16* const lB0b = Bs0 + (wave * 32 + 16) * 32;
  bf16* const lB1 = Bs1 + wave * 32 * 32;
  bf16* const lB1b = Bs1 + (wave * 32 + 16) * 32;

  f32x4 acc[4][4] = {};
  for (int k0 = 0; k0 < 256; k0 += 64) {
    gld_lds16(gA0 + k0, lA0);
    gld_lds16(gA1 + k0, lA0b);
    gld_lds16(gA0 + k0 + 32, lA1);
    gld_lds16(gA1 + k0 + 32, lA1b);
    gld_lds16(gB0 + k0, lB0);
    gld_lds16(gB1 + k0, lB0b);
    gld_lds16(gB0 + k0 + 32, lB1);
    gld_lds16(gB1 + k0 + 32, lB1b);
    __syncthreads();
#pragma unroll
    for (int ks = 0; ks < 2; ++ks) {
      const bf16* aRd = (ks ? As1 : As0) + (wr * 64 + l16) * 32 + qsw * 8;
      const bf16* bRd = (ks ? Bs1 : Bs0) + (wc * 64 + l16) * 32 + qsw * 8;
      bf16x8 af[4], bfr[4];
#pragma unroll
      for (int i = 0; i < 4; ++i) {
        af[i] = *(const bf16x8*)(aRd + i * 16 * 32);
        bfr[i] = *(const bf16x8*)(bRd + i * 16 * 32);
      }
#pragma unroll
      for (int mi = 0; mi < 4; ++mi)
#pragma unroll
        for (int ni = 0; ni < 4; ++ni)
          acc[mi][ni] = MFMA16(bfr[ni], af[mi], acc[mi][ni]);
    }
    __syncthreads();
  }

  const int seg = colBlk >> 10;  // 0: policy, 1: dyn-z (linear), 2: value
  bf16* const Cp = (seg == 0) ? Ha : (seg == 1) ? Hp : Hv;
  const int cShift = seg << 10;
  const float* const bp = (seg == 2) ? (vbiasT - 2048) : pdb1;
#pragma unroll
  for (int mi = 0; mi < 4; ++mi) {
    const int row = rowBlk + wr * 64 + mi * 16 + l16;
#pragma unroll
    for (int ni = 0; ni < 4; ++ni) {
      const int col0 = colBlk + wc * 64 + ni * 16 + quad * 4;
      const f32x4 bb = *(const f32x4*)(bp + col0);
      bf16x4 o;
#pragma unroll
      for (int r = 0; r < 4; ++r) {
        float x = acc[mi][ni][r] + bb[r];
        if (seg != 1) x = silu(x);
        o[r] = (bf16)x;
      }
      *(bf16x4*)(Cp + (size_t)row * 1024 + (col0 - cShift)) = o;
    }
  }
}

// ---- 256x256 8-phase GEMM body (shared by gemm256 and gemm256_dual) ---
template <int NT, int EPI>
__device__ __forceinline__ void gemm256_body(
    const bf16* __restrict__ A, const bf16* __restrict__ Bt, int rowBlk,
    int colBlk, const float* __restrict__ bias, const float* __restrict__ aux,
    bf16* __restrict__ C1, float* __restrict__ efe, float disc,
    bf16 (*sAB)[2][256 * 64]) {
  constexpr int K = NT * 64;
  const int tid = threadIdx.x, wave = tid >> 6, lane = tid & 63;
  const int quad = lane >> 4, l16 = lane & 15;
  const int wr = wave >> 2, wc = wave & 3;  // 2 x 4 wave grid

  const int j8 = lane >> 3;
  const int c16e = ((lane & 7) ^ j8) * 8;  // inverse-swizzled source col
  const bf16* gAs = A + (size_t)(rowBlk + wave * 16 + j8) * K + c16e;
  const bf16* gBs = Bt + (size_t)(colBlk + wave * 16 + j8) * K + c16e;

#define STAGE_A(hh, tt, bb)                                           \
  do {                                                                \
    const bf16* g_ = gAs + (hh) * 128 * K + (tt) * 64;                \
    bf16* l_ = &sAB[(bb)][0][((hh) * 128 + wave * 16) * 64];          \
    gld_lds16(g_, l_);                                                \
    gld_lds16(g_ + 8 * K, l_ + 8 * 64);                               \
  } while (0)
#define STAGE_B(hh, tt, bb)                                           \
  do {                                                                \
    const bf16* g_ = gBs + (hh) * 128 * K + (tt) * 64;                \
    bf16* l_ = &sAB[(bb)][1][((hh) * 128 + wave * 16) * 64];          \
    gld_lds16(g_, l_);                                                \
    gld_lds16(g_ + 8 * K, l_ + 8 * 64);                               \
  } while (0)

  const int k0x = (quad * 8) ^ ((l16 & 7) << 3);
  const int aOff = (wr * 128 + l16) * 64 + k0x;
  const int bOff = (wc * 64 + l16) * 64 + k0x;

  bf16x8 bAf[4][2], bBf[2][2], bB2f[2][2];
  f32x4 acc[8][4] = {};

  // prologue: tile0 fully + tile1 B-halves
  STAGE_A(0, 0, 0);
  STAGE_A(1, 0, 0);
  STAGE_B(0, 0, 0);
  STAGE_B(1, 0, 0);
  STAGE_B(0, 1, 1);
  STAGE_B(1, 1, 1);
  VMCNT(4);
  SBAR();
  SCHED0();

#pragma unroll 2
  for (int t = 0; t < NT; ++t) {
    const int buf = t & 1;
    const bf16* lA = &sAB[buf][0][0];
    const bf16* lB = &sAB[buf][1][0];

    // q0: read A m0-3 + B n0-1; stage A0(t+1); MFMA q0
#pragma unroll
    for (int m = 0; m < 4; ++m)
#pragma unroll
      for (int ks = 0; ks < 2; ++ks)
        bAf[m][ks] = *(const bf16x8*)(lA + ((aOff + m * 1024) ^ (ks << 5)));
#pragma unroll
    for (int n = 0; n < 2; ++n)
#pragma unroll
      for (int ks = 0; ks < 2; ++ks)
        bBf[n][ks] = *(const bf16x8*)(lB + ((bOff + n * 1024) ^ (ks << 5)));
    if (t + 1 < NT) STAGE_A(0, t + 1, buf ^ 1);
    SBAR();
    LGKMCNT0();
    SCHED0();
    __builtin_amdgcn_s_setprio(1);
#pragma unroll
    for (int ks = 0; ks < 2; ++ks)
#pragma unroll
      for (int m = 0; m < 4; ++m)
#pragma unroll
        for (int n = 0; n < 2; ++n)
          acc[m][n] = MFMA16(bBf[n][ks], bAf[m][ks], acc[m][n]);
    __builtin_amdgcn_s_setprio(0);
    SBAR();
    SCHED0();

    // q1: read B n2-3; stage A1(t+1); MFMA m0-3 x n2-3
#pragma unroll
    for (int n = 0; n < 2; ++n)
#pragma unroll
      for (int ks = 0; ks < 2; ++ks)
        bB2f[n][ks] =
            *(const bf16x8*)(lB + ((bOff + (n + 2) * 1024) ^ (ks << 5)));
    if (t + 1 < NT) STAGE_A(1, t + 1, buf ^ 1);
    SBAR();
    LGKMCNT0();
    SCHED0();
    __builtin_amdgcn_s_setprio(1);
#pragma unroll
    for (int ks = 0; ks < 2; ++ks)
#pragma unroll
      for (int m = 0; m < 4; ++m)
#pragma unroll
        for (int n = 0; n < 2; ++n)
          acc[m][n + 2] = MFMA16(bB2f[n][ks], bAf[m][ks], acc[m][n + 2]);
    __builtin_amdgcn_s_setprio(0);
    SBAR();
    SCHED0();

    // q2: read A m4-7; stage B0(t+2); MFMA m4-7 x n2-3
#pragma unroll
    for (int m = 0; m < 4; ++m)
#pragma unroll
      for (int ks = 0; ks < 2; ++ks)
        bAf[m][ks] =
            *(const bf16x8*)(lA + ((aOff + (m + 4) * 1024) ^ (ks << 5)));
    if (t + 2 < NT) STAGE_B(0, t + 2, buf);
    SBAR();
    LGKMCNT0();
    SCHED0();
    __builtin_amdgcn_s_setprio(1);
#pragma unroll
    for (int ks = 0; ks < 2; ++ks)
#pragma unroll
      for (int m = 0; m < 4; ++m)
#pragma unroll
        for (int n = 0; n < 2; ++n)
          acc[m + 4][n + 2] =
              MFMA16(bB2f[n][ks], bAf[m][ks], acc[m + 4][n + 2]);
    __builtin_amdgcn_s_setprio(0);
    SBAR();
    SCHED0();

    // q3: no reads; stage B1(t+2); MFMA m4-7 x n0-1; counted vmcnt
    if (t + 2 < NT) STAGE_B(1, t + 2, buf);
    SBAR();
    SCHED0();
    __builtin_amdgcn_s_setprio(1);
#pragma unroll
    for (int ks = 0; ks < 2; ++ks)
#pragma unroll
      for (int m = 0; m < 4; ++m)
#pragma unroll
        for (int n = 0; n < 2; ++n)
          acc[m + 4][n] = MFMA16(bBf[n][ks], bAf[m][ks], acc[m + 4][n]);
    __builtin_amdgcn_s_setprio(0);
    if (t < NT - 2) {
      VMCNT(4);
    } else {
      VMCNT(0);
    }
    SBAR();
    SCHED0();
  }
#undef STAGE_A
#undef STAGE_B

  if constexpr (EPI == 0) {  // silu(acc + bias) -> C1, ldc=1024
#pragma unroll
    for (int m = 0; m < 8; ++m) {
      const int row = rowBlk + wr * 128 + m * 16 + l16;
#pragma unroll
      for (int n = 0; n < 4; ++n) {
        const int gcol = colBlk + wc * 64 + n * 16 + quad * 4;
        const f32x4 bb = *(const f32x4*)(bias + gcol);
        bf16x4 o;
#pragma unroll
        for (int r = 0; r < 4; ++r) o[r] = (bf16)silu(acc[m][n][r] + bb[r]);
        *(bf16x4*)(C1 + (size_t)row * 1024 + gcol) = o;
      }
    }
  } else {  // EPI == 1: value L2 + vW3 dot -> efe
#pragma unroll
    for (int m = 0; m < 8; ++m) {
      const int row = rowBlk + wr * 128 + m * 16 + l16;
      float p = 0.f;
#pragma unroll
      for (int n = 0; n < 4; ++n) {
        const int gcol = colBlk + wc * 64 + n * 16 + quad * 4;
        const f32x4 bb = *(const f32x4*)(bias + gcol);
        const f32x4 w3 = *(const f32x4*)(aux + gcol);
#pragma unroll
        for (int r = 0; r < 4; ++r) p += silu(acc[m][n][r] + bb[r]) * w3[r];
      }
      p += __shfl_xor(p, 16);
      p += __shfl_xor(p, 32);
      if (quad == 0) atomicAdd(efe + row, disc * p);
    }
  }
}

template <int NT, int EPI>
__global__ __launch_bounds__(512, 2) void gemm256(
    const bf16* __restrict__ A, const bf16* __restrict__ Bt, int nCol,
    const float* __restrict__ bias, const float* __restrict__ aux,
    bf16* __restrict__ C1, float* __restrict__ efe, float disc) {
  static_assert(NT >= 2, "need at least 2 K-tiles");
  __shared__ alignas(16) bf16 sAB[2][2][256 * 64];
  const int nwg = gridDim.x, flat = blockIdx.x;
  const int lid = (flat & 7) * (nwg >> 3) + (flat >> 3);
  const int rowBlk = (lid / nCol) * 256, colBlk = (lid % nCol) * 256;
  gemm256_body<NT, EPI>(A, Bt, rowBlk, colBlk, bias, aux, C1, efe, disc, sAB);
}

// fused {policy-L2 (EPI0), value-L2+dot (EPI1)}: grid 256, TEMPORAL.
template <int NT>
__global__ __launch_bounds__(512, 2) void gemm256_dual(
    const bf16* __restrict__ A0, const bf16* __restrict__ Bt0,
    const float* __restrict__ bias0, bf16* __restrict__ C0,
    const bf16* __restrict__ A1, const bf16* __restrict__ Bt1,
    const float* __restrict__ bias1, const float* __restrict__ aux1,
    float* __restrict__ efe, float disc) {
  __shared__ alignas(16) bf16 sAB[2][2][256 * 64];
  const int flat = blockIdx.x;  // 256 blocks
  const int seq = (flat & 7) * 32 + (flat >> 3);  // 0..255, XCD-chunked
  const int rowBlk = (seq >> 2) * 256, colBlk = (seq & 3) * 256;
  gemm256_body<NT, 0>(A0, Bt0, rowBlk, colBlk, bias0, nullptr, C0, nullptr,
                      0.f, sAB);
  gemm256_body<NT, 1>(A1, Bt1, rowBlk, colBlk, bias1, aux1, nullptr, efe,
                      disc, sAB);
}

// ---- dynamics L3 + z_next + KL partials, col-fused --------------------
// One block = 64 rows x ALL 256 cols (acc[16]); grid 256 = 1 block/CU,
// single round. Hc read once (was twice); s_n/s_c plain stores (were
// atomics). dbuf + counted VMCNT(10) (10 loads/thread per stage).
__global__ __launch_bounds__(256) void gemm_dyn3(
    const bf16* __restrict__ A, const bf16* __restrict__ Bt,
    const float* __restrict__ db3, float* __restrict__ Zf,
    bf16* __restrict__ Zb, float* __restrict__ s_n, float* __restrict__ s_c) {
  __shared__ alignas(16) bf16 PA[2][2][64 * 32];
  __shared__ alignas(16) bf16 PB[2][2][256 * 32];
  const int tid = threadIdx.x, wave = tid >> 6, lane = tid & 63;
  const int quad = lane >> 4, l16 = lane & 15;
  const int rowBlk = blockIdx.x * 64;
  const int srow = lane >> 2;
  const int skel = (((lane & 3) ^ ((lane >> 3) & 3)) * 8);
  const int qsw = quad ^ ((l16 >> 1) & 3);

  const bf16* gA = A + (size_t)(rowBlk + wave * 16 + srow) * 1024 + skel;
  // wave stages B rows [wave*64, wave*64+64): 4 groups of 16
  const bf16* gB = Bt + (size_t)(wave * 64 + srow) * 1024 + skel;

#define STGD(t, b)                                                        \
  do {                                                                    \
    const int k0_ = (t)*64;                                               \
    gld_lds16(gA + k0_, &PA[b][0][wave * 512]);                           \
    gld_lds16(gA + k0_ + 32, &PA[b][1][wave * 512]);                      \
    _Pragma("unroll") for (int j = 0; j < 4; ++j) {                       \
      gld_lds16(gB + (size_t)(j * 16) * 1024 + k0_,                       \
                &PB[b][0][(wave * 64 + j * 16) * 32]);                    \
      gld_lds16(gB + (size_t)(j * 16) * 1024 + k0_ + 32,                  \
                &PB[b][1][(wave * 64 + j * 16) * 32]);                    \
    }                                                                     \
  } while (0)

  f32x4 acc[16] = {};
  STGD(0, 0);
  STGD(1, 1);
  VMCNT(10);
  SBAR();
  SCHED0();
#pragma unroll 2
  for (int t = 0; t < 16; ++t) {
    const int b = t & 1;
#pragma unroll
    for (int ks = 0; ks < 2; ++ks) {
      const bf16* aRd = &PA[b][ks][(wave * 16 + l16) * 32 + qsw * 8];
      const bf16* bRd = &PB[b][ks][l16 * 32 + qsw * 8];
      const bf16x8 af = *(const bf16x8*)aRd;
#pragma unroll
      for (int ni = 0; ni < 16; ++ni) {
        const bf16x8 bfr = *(const bf16x8*)(bRd + ni * 16 * 32);
        acc[ni] = MFMA16(bfr, af, acc[ni]);
      }
    }
    if (t == 15) break;
    SBAR();
    SCHED0();
    if (t < 14) {
      STGD(t + 2, b);
      VMCNT(10);
    } else {
      VMCNT(0);
    }
    SBAR();
    SCHED0();
  }
#undef STGD

  const int row = rowBlk + wave * 16 + l16;
  float pn = 0.f, pc = 0.f;
#pragma unroll
  for (int ni = 0; ni < 16; ++ni) {
    const int col0 = ni * 16 + quad * 4;
    const f32x4 b4 = *(const f32x4*)(db3 + col0);
    float* zp = Zf + (size_t)row * 256 + col0;
    const f32x4 z = *(const f32x4*)zp;
    f32x4 zn;
    bf16x4 o;
#pragma unroll
    for (int r = 0; r < 4; ++r) {
      zn[r] = z[r] + acc[ni][r] + b4[r];
      pn += zn[r] * zn[r];
      pc += z[r] * zn[r];
      o[r] = (bf16)zn[r];
    }
    *(f32x4*)zp = zn;
    *(bf16x4*)(Zb + (size_t)row * 256 + col0) = o;
  }
  pn += __shfl_xor(pn, 16);
  pn += __shfl_xor(pn, 32);
  pc += __shfl_xor(pc, 16);
  pc += __shfl_xor(pc, 32);
  if (quad == 0) {  // full row in this block -> plain stores
    s_n[row] = pn;
    s_c[row] = pc;
  }
}

// ---- batched KL epilogue: all 5 steps at once -------------------------
__global__ void kl_batch(const float* __restrict__ sz0,
                         const float* __restrict__ snAll,
                         const float* __restrict__ scAll,
                         float* __restrict__ efe) {
  const int m = blockIdx.x * 256 + threadIdx.x;
  float sz = sz0[m];
  float disc = 1.f, acc = 0.f;
  for (int t = 0; t < HORIZON; ++t) {
    const float sn = snAll[t * MR + m], sc = scAll[t * MR + m];
    const float nz = sqrtf(sz) + 1e-8f, nn = sqrtf(sn) + 1e-8f;
    const float kl =
        0.5f * (sz / (nz * nz) + sn / (nn * nn) - 2.f * sc / (nz * nn));
    acc += disc * log1pf(fmaxf(kl, 0.f));
    sz = sn;
    disc *= 0.99f;
  }
  efe[m] += acc;
}

// ---- heads4: split-K heads + dynamics-L1 completion -------------------
// Per-wave panels (wave owns K-quarter) -> NO barriers in k-loop; per-wave
// dbuf + counted VMCNT(5) keeps one tile in flight while computing.
__global__ __launch_bounds__(256) void heads4(
    const bf16* __restrict__ H, const bf16* __restrict__ Wt,
    const float* __restrict__ pbm, const float* __restrict__ pbs,
    const float* __restrict__ noise, const bf16* __restrict__ preD,
    const bf16* __restrict__ dW1at, bf16* __restrict__ Hd,
    float* __restrict__ efe, int t, float disc, int rmask) {
  __shared__ alignas(16) bf16 As[2][4 * 16 * 32];
  __shared__ alignas(16) bf16 Bs[2][4 * 64 * 32];  // Bs[0] aliased as f32 red
  __shared__ alignas(16) bf16 LAct[16 * 32];
  const int tid = threadIdx.x, wave = tid >> 6, lane = tid & 63;
  const int quad = lane >> 4, l16 = lane & 15;
  const int rowBlk = blockIdx.x * 16;
  const int srow = lane >> 2;
  const int skel = (((lane & 3) ^ ((lane >> 3) & 3)) * 8);
  const int qsw = quad ^ ((l16 >> 1) & 3);
  const int kw = wave * 256;

  const bf16* gA = H + (size_t)((rowBlk + srow) & rmask) * 1024 + kw + skel;

#define STGH(kt, b)                                                         \
  do {                                                                      \
    gld_lds16(gA + (kt) * 32, &As[b][wave * 512]);                          \
    _Pragma("unroll") for (int j = 0; j < 4; ++j) gld_lds16(                \
        Wt + (size_t)(j * 16 + srow) * 1024 + kw + (kt) * 32 + skel,        \
        &Bs[b][wave * 2048 + j * 512]);                                     \
  } while (0)

  f32x4 acc[4] = {};
  STGH(0, 0);
  STGH(1, 1);  // 10 loads in flight
#pragma unroll
  for (int kt = 0; kt < 8; ++kt) {
    const int b = kt & 1;
    if (kt < 7) {
      VMCNT(5);  // tile kt landed; tile kt+1 stays in flight
    } else {
      VMCNT(0);
    }
    SCHED0();
    const bf16x8 af =
        *(const bf16x8*)(&As[b][wave * 512] + l16 * 32 + qsw * 8);
#pragma unroll
    for (int ni = 0; ni < 4; ++ni) {
      const bf16x8 bfr =
          *(const bf16x8*)(&Bs[b][wave * 2048] + (ni * 16 + l16) * 32 + qsw * 8);
      acc[ni] = MFMA16(bfr, af, acc[ni]);
    }
    SCHED0();  // pin: ds_reads/MFMA above, restage below
    if (kt < 6) {
      LGKMCNT0();  // ds_reads of buf b fully retired before overwrite
      STGH(kt + 2, b);
    }
  }
#undef STGH

  // cross-wave reduction: partials through Bs[0]-aliased f32 scratch
  float* red = (float*)Bs;  // wave w's slice aliases its OWN Bs[0] panel
#pragma unroll
  for (int ni = 0; ni < 4; ++ni)
    *(f32x4*)(red + wave * 1024 + ni * 256 + lane * 4) = acc[ni];
  __syncthreads();
#pragma unroll
  for (int ni = 0; ni < 4; ++ni) {
    f32x4 s = *(const f32x4*)(red + ni * 256 + lane * 4);
#pragma unroll
    for (int w2 = 1; w2 < 4; ++w2) {
      const f32x4 p = *(const f32x4*)(red + w2 * 1024 + ni * 256 + lane * 4);
#pragma unroll
      for (int r = 0; r < 4; ++r) s[r] += p[r];
    }
    acc[ni] = s;
  }

  // action + entropy (computed redundantly by all waves; wave0 writes)
  const int row = rowBlk + l16;
  const int n = row >> 10, b2 = row & 1023;
  float ent = 0.f;
#pragma unroll
  for (int ni = 0; ni < 2; ++ni) {
    const int col0 = ni * 16 + quad * 4;
    const f32x4 bm4 = *(const f32x4*)(pbm + col0);
    const f32x4 bs4 = *(const f32x4*)(pbs + col0);
    const f32x4 ep4 =
        *(const f32x4*)(noise + (((size_t)(n * 5 + t) * 1024 + b2) * 32 + col0));
    bf16x4 o;
#pragma unroll
    for (int r = 0; r < 4; ++r) {
      const float mean = acc[ni][r] + bm4[r];
      float ls = acc[ni + 2][r] + bs4[r];
      ls = fminf(fmaxf(ls, -5.f), 2.f);
      o[r] = (bf16)(mean + __expf(ls) * ep4[r]);
      ent += ENT_C + ls;
    }
    if (wave == 0) *(bf16x4*)(LAct + l16 * 32 + col0) = o;
  }
  ent += __shfl_xor(ent, 16);
  ent += __shfl_xor(ent, 32);
  if (wave == 0 && quad == 0) efe[row] += disc * (-0.1f) * ent;
  __syncthreads();  // LAct ready

  // rank-32 completion: wave w handles col-tiles [w*16, w*16+16)
  const int prow = row & rmask;
  const bf16x8 af2 = *(const bf16x8*)(LAct + l16 * 32 + quad * 8);
#pragma unroll 4
  for (int ci = 0; ci < 16; ++ci) {
    const int ct = wave * 16 + ci;
    const bf16x8 wf =
        *(const bf16x8*)(dW1at + (size_t)(ct * 16 + l16) * 32 + quad * 8);
    f32x4 a = {};
    a = MFMA16(wf, af2, a);
    const int col0 = ct * 16 + quad * 4;
    const bf16x4 pd = *(const bf16x4*)(preD + (size_t)prow * 1024 + col0);
    bf16x4 o;
#pragma unroll
    for (int r = 0; r < 4; ++r) o[r] = (bf16)silu(a[r] + (float)pd[r]);
    *(bf16x4*)(Hd + (size_t)row * 1024 + col0) = o;
  }
}

// ---- unified prep: coalesced tiled transposes + vbias + init ----------
__global__ __launch_bounds__(256) void prep_tr(
    const float* __restrict__ pW1, const float* __restrict__ dW1,
    const float* __restrict__ vW1, const float* __restrict__ pW2,
    const float* __restrict__ dW2, const float* __restrict__ dW3,
    const float* __restrict__ vW2, const float* __restrict__ pWm,
    const float* __restrict__ pWs, const float* __restrict__ pb1,
    const float* __restrict__ db1, const float* __restrict__ vb1,
    const float* __restrict__ latent, bf16* __restrict__ pdW1vt,
    bf16* __restrict__ pW2t, bf16* __restrict__ pHt,
    bf16* __restrict__ dW1at, bf16* __restrict__ dW2t,
    bf16* __restrict__ dW3t, bf16* __restrict__ vW2t,
    float* __restrict__ pdb1, float* __restrict__ vbias,
    float* __restrict__ Zf, bf16* __restrict__ Zb0, float* __restrict__ efe,
    float* __restrict__ sz0, float* __restrict__ snAll,
    float* __restrict__ scAll) {
  int bid = blockIdx.x;
  if (bid == 1072) {  // pdb1
    for (int i = threadIdx.x; i < 2048; i += 256)
      pdb1[i] = (i < 1024) ? pb1[i] : db1[i - 1024];
    return;
  }
  if (bid >= 1073 && bid < 1093) {  // vbias
    const int idx = (bid - 1073) * 256 + threadIdx.x;  // < 5120
    const int t = idx >> 10, j = idx & 1023;
    float s = vb1[j];
    const float lt = (float)t;
    for (int i = 0; i < 64; ++i) {
      const float f = expf(-9.210340371976184f * (float)i / 64.f);
      const float ang = lt * f;
      s += sinf(ang) * vW1[(size_t)(256 + i) * 1024 + j];
      s += cosf(ang) * vW1[(size_t)(256 + 64 + i) * 1024 + j];
    }
    vbias[idx] = s;
    return;
  }
  if (bid >= 1093) {  // init: 4 rows/block, wave per row
    const int wave = threadIdx.x >> 6, lane = threadIdx.x & 63;
    const int row = (bid - 1093) * 4 + wave;
    const f32x4 z = *(const f32x4*)(latent + (size_t)(row & 1023) * 256 + lane * 4);
    *(f32x4*)(Zf + (size_t)row * 256 + lane * 4) = z;
    if (row < 1024) {
      bf16x4 o = {(bf16)z[0], (bf16)z[1], (bf16)z[2], (bf16)z[3]};
      *(bf16x4*)(Zb0 + (size_t)row * 256 + lane * 4) = o;
    }
    float s = z[0] * z[0] + z[1] * z[1] + z[2] * z[2] + z[3] * z[3];
#pragma unroll
    for (int m = 1; m < 64; m <<= 1) s += __shfl_xor(s, m);
    if (lane == 0) {
      sz0[row] = s;
      efe[row] = 0.f;
    }
    if (lane < HORIZON) {
      snAll[lane * MR + row] = 0.f;
      scAll[lane * MR + row] = 0.f;
    }
    return;
  }
  // ---- tiled transpose segments ----
  const float* in;
  bf16* out;
  int K, N, ldin, ro = 0;
  if (bid < 64) { in = pW1; out = pdW1vt; K = 256; N = 1024; ldin = 1024; }
  else if (bid < 128) { bid -= 64; in = dW1; out = pdW1vt + 1024 * 256; K = 256; N = 1024; ldin = 1024; }
  else if (bid < 192) { bid -= 128; in = vW1; out = pdW1vt + 2048 * 256; K = 256; N = 1024; ldin = 1024; }
  else if (bid < 448) { bid -= 192; in = pW2; out = pW2t; K = 1024; N = 1024; ldin = 1024; }
  else if (bid < 704) { bid -= 448; in = dW2; out = dW2t; K = 1024; N = 1024; ldin = 1024; }
  else if (bid < 960) { bid -= 704; in = vW2; out = vW2t; K = 1024; N = 1024; ldin = 1024; }
  else if (bid < 1024) { bid -= 960; in = dW3; out = dW3t; K = 1024; N = 256; ldin = 256; }
  else if (bid < 1040) { bid -= 1024; in = dW1; out = dW1at; K = 32; N = 1024; ldin = 1024; ro = 256; }
  else if (bid < 1056) { bid -= 1040; in = pWm; out = pHt; K = 1024; N = 32; ldin = 32; }
  else { bid -= 1056; in = pWs; out = pHt + 32 * 1024; K = 1024; N = 32; ldin = 32; }

  const int ktiles = (K + 63) >> 6;
  const int k0 = (bid % ktiles) * 64, n0 = (bid / ktiles) * 64;
  __shared__ float tile[64][65];
  const int tx = threadIdx.x & 63, ty = threadIdx.x >> 6;
#pragma unroll
  for (int i = 0; i < 16; ++i) {
    const int k = k0 + ty + i * 4;
    if (k < K && n0 + tx < N)
      tile[ty + i * 4][tx] = in[(size_t)(ro + k) * ldin + n0 + tx];
  }
  __syncthreads();
#pragma unroll
  for (int i = 0; i < 16; ++i) {
    const int n = n0 + ty + i * 4;
    if (n < N && k0 + tx < K)
      out[(size_t)n * K + k0 + tx] = (bf16)tile[tx][ty + i * 4];
  }
}

__global__ void finalize(const float* __restrict__ efe,
                         const float* __restrict__ vb3,
                         float* __restrict__ out) {
  const int b = blockIdx.x * 256 + threadIdx.x;  // 1024
  float s = 0.f;
#pragma unroll
  for (int n = 0; n < 16; ++n) s += efe[n * 1024 + b];
  out[b] = s * (1.f / 16.f) + SUMDISC * vb3[0];
}

extern "C" void kernel_launch(void* const* d_in, const int* in_sizes, int n_in,
                              void* d_out, int out_size, void* d_ws,
                              size_t ws_size, hipStream_t stream) {
  const float* latent = (const float*)d_in[0];
  const float* noise = (const float*)d_in[1];
  const float* pW1 = (const float*)d_in[2];
  const float* pb1 = (const float*)d_in[3];
  const float* pW2 = (const float*)d_in[4];
  const float* pb2 = (const float*)d_in[5];
  const float* pWm = (const float*)d_in[6];
  const float* pbm = (const float*)d_in[7];
  const float* pWs = (const float*)d_in[8];
  const float* pbs = (const float*)d_in[9];
  const float* dW1 = (const float*)d_in[10];
  const float* db1 = (const float*)d_in[11];
  const float* dW2 = (const float*)d_in[12];
  const float* db2 = (const float*)d_in[13];
  const float* dW3 = (const float*)d_in[14];
  const float* db3 = (const float*)d_in[15];
  const float* vW1 = (const float*)d_in[16];
  const float* vb1 = (const float*)d_in[17];
  const float* vW2 = (const float*)d_in[18];
  const float* vb2 = (const float*)d_in[19];
  const float* vW3 = (const float*)d_in[20];
  const float* vb3 = (const float*)d_in[21];

  char* w = (char*)d_ws;
  size_t off = 0;
  auto take = [&](size_t bytes) -> void* {
    void* p = (void*)(w + off);
    off = (off + bytes + 255) & ~(size_t)255;
    return p;
  };
  bf16* pdW1vt = (bf16*)take(3072ull * 256 * 2);  // [pW1|dW1z|vW1]^T
  float* pdb1 = (float*)take(2048ull * 4);
  bf16* pW2t = (bf16*)take(1024ull * 1024 * 2);
  bf16* pHt = (bf16*)take(64ull * 1024 * 2);
  bf16* dW1at = (bf16*)take(1024ull * 32 * 2);
  bf16* dW2t = (bf16*)take(1024ull * 1024 * 2);
  bf16* dW3t = (bf16*)take(256ull * 1024 * 2);
  bf16* vW2t = (bf16*)take(1024ull * 1024 * 2);
  float* vbias = (float*)take(5ull * 1024 * 4);
  bf16* Zb0 = (bf16*)take(1024ull * 256 * 2);      // z0 bf16, shared rows
  bf16* Zb = (bf16*)take((size_t)MR * 256 * 2);    // z_t bf16 (single buf)
  float* Zf = (float*)take((size_t)MR * 256 * 4);  // fp32 master z
  float* efe = (float*)take((size_t)MR * 4);
  float* sz0 = (float*)take((size_t)MR * 4);
  float* snAll = (float*)take(5ull * MR * 4);
  float* scAll = (float*)take(5ull * MR * 4);
  bf16* Ha = (bf16*)take((size_t)MR * 1024 * 2);
  bf16* Hc = (bf16*)take((size_t)MR * 1024 * 2);
  bf16* Hp = (bf16*)take((size_t)MR * 1024 * 2);
  bf16* Hv = (bf16*)take((size_t)MR * 1024 * 2);
  bf16* vW1t = pdW1vt + (size_t)2048 * 256;  // value-L1 weights (tail step)

  const dim3 blk(256), blk2(512);
  const int BIG = 1 << 30;
  // prep_tr: 1072 transpose tiles + pdb1 + 20 vbias + 4096 init blocks
  prep_tr<<<dim3(1093 + MR / 4), blk, 0, stream>>>(
      pW1, dW1, vW1, pW2, dW2, dW3, vW2, pWm, pWs, pb1, db1, vb1, latent,
      pdW1vt, pW2t, pHt, dW1at, dW2t, dW3t, vW2t, pdb1, vbias, Zf, Zb0, efe,
      sz0, snAll, scAll);

  float disc = 1.f, dprev = 1.f;
  for (int s = 0; s < HORIZON; ++s) {
    const int rmask = (s == 0) ? 1023 : 0x7FFFFFFF;
    if (s == 0) {
      // [policy L1 | dyn L1z] only: M=1024 (shared latent), N=2048
      gemm128<<<dim3(8, 16), blk, 0, stream>>>(Zb0, 256, 256, pdW1vt, pdb1,
                                               1024, Ha, Hp, 1024);
      // policy L2 at M=1024
      gemm128<<<dim3(8, 8), blk, 0, stream>>>(Ha, 1024, 1024, pW2t, pb2, BIG,
                                              Hc, Hc, 1024);
    } else {
      // trunk + value-L1 for pragmatic(s-1) on z_s: N=3072, K=256
      gemm_pd1v<<<dim3(128, 24), blk, 0, stream>>>(
          Zb, pdW1vt, pdb1, vbias + (s - 1) * 1024, Ha, Hp, Hv);
      // fused {policy L2 -> Hc} then {value L2 + vW3 dot -> efe}, grid 256
      gemm256_dual<16><<<dim3(256), blk2, 0, stream>>>(
          Ha, pW2t, pb2, Hc, Hv, vW2t, vb2, vW3, efe, dprev);
    }
    // heads + dyn-L1 completion: Hc,Hp (masked rows) -> action/ent, Hd -> Ha
    heads4<<<dim3(MR / 16), blk, 0, stream>>>(Hc, pHt, pbm, pbs, noise, Hp,
                                              dW1at, Ha, efe, s, disc, rmask);
    // dynamics L2: Ha -> Hc (8-phase 256-tile)
    gemm256<16, 0><<<dim3(256), blk2, 0, stream>>>(Ha, dW2t, 4, db2, nullptr,
                                                   Hc, nullptr, 0.f);
    // dynamics L3 fused with z_next / KL partials; col-fused, grid 256
    gemm_dyn3<<<dim3(MR / 64), blk, 0, stream>>>(
        Hc, dW3t, db3, Zf, Zb, snAll + (size_t)s * MR, scAll + (size_t)s * MR);
    dprev = disc;
    disc *= 0.99f;
  }

  kl_batch<<<dim3(MR / 256), blk, 0, stream>>>(sz0, snAll, scAll, efe);

  // final pragmatic(4) on z_5: value L1 (dbuf 2-phase, K=256) then L2+dot
  gemm128<<<dim3(128, 8), blk, 0, stream>>>(Zb, 256, 256, vW1t,
                                            vbias + 4 * 1024, BIG, Hv, Hv,
                                            1024);
  gemm256<16, 1><<<dim3(256), blk2, 0, stream>>>(Hv, vW2t, 4, vb2, vW3,
                                                 nullptr, efe, dprev);
  finalize<<<dim3(4), blk, 0, stream>>>(efe, vb3, (float*)d_out);
}

// Round 13
// 1019.977 us; speedup vs baseline: 1.0204x; 1.0133x over previous
//
#include <hip/hip_runtime.h>
#include <cstdint>
#include <cstddef>
#include <cmath>

// DiffusionActiveInference on MI355X (gfx950).
// R19: consolidation to best measured build (R16, 1021.2us). R18's dyn3
// col-fusion regressed (+2.5us/dispatch): 80KB LDS -> 1 block/CU lost the
// cross-block TLP that covers the exposed drains - the same law that
// killed pd1v-dbuf/sbuf256/persistent-B. Revert dyn3 to the R16 2-col-
// split (48KB, grid (256,2), VMCNT(6), atomics). All other kernels
// byte-identical to R16. Established optima: pd1v=sbuf128 (5 variants
// tested), dual=temporal-fused 8-phase (897 TF, structure ceiling),
// heads4=per-wave-dbuf-nobarrier, dyn3=2-col-split dbuf.

typedef __bf16 bf16;
typedef __attribute__((ext_vector_type(8))) __bf16 bf16x8;
typedef __attribute__((ext_vector_type(4))) __bf16 bf16x4;
typedef __attribute__((ext_vector_type(4))) float f32x4;

static constexpr int BATCH = 1024, NTRAJ = 16, HORIZON = 5;
static constexpr int MR = NTRAJ * BATCH;  // 16384 GEMM rows
static constexpr float ENT_C = 1.4189385332046727f;  // 0.5*(1+log(2*pi))
static constexpr float SUMDISC = 4.90099501f;        // sum 0.99^t, t=0..4

// ---- async global->LDS, 16B per lane ----------------------------------
__device__ __forceinline__ void gld_lds16(const bf16* g, const bf16* l) {
  typedef __attribute__((address_space(1))) const uint32_t gq_t;
  typedef __attribute__((address_space(3))) uint32_t lq_t;
  gq_t* gp = (gq_t*)(uintptr_t)g;
  lq_t* lp = (lq_t*)(uint32_t)(uintptr_t)l;
  __builtin_amdgcn_global_load_lds(gp, lp, 16, 0, 0);
}

// silu via raw v_rcp_f32: avoids the IEEE div expansion (~10 VALU ops).
__device__ __forceinline__ float silu(float x) {
  return x * __builtin_amdgcn_rcpf(1.f + __expf(-x));
}

#define MFMA16(a, b, c) __builtin_amdgcn_mfma_f32_16x16x32_bf16((a), (b), (c), 0, 0, 0)
#define SBAR() __builtin_amdgcn_s_barrier()
#define SCHED0() __builtin_amdgcn_sched_barrier(0)
#define VMCNT(n) asm volatile("s_waitcnt vmcnt(" #n ")" ::: "memory")
#define LGKMCNT0() asm volatile("s_waitcnt lgkmcnt(0)" ::: "memory")

// ---- generic GEMM: C = maybe_silu(A[M,K](lda) @ Bt[N,K]^T + bias) -----
// dbuf 2-phase 128-tile, counted vmcnt. K = nt*64, nt >= 2.
__global__ __launch_bounds__(256) void gemm128(
    const bf16* __restrict__ A, int lda, int K, const bf16* __restrict__ Bt,
    const float* __restrict__ bias, int act_cols,
    bf16* __restrict__ C1, bf16* __restrict__ C2, int ldc) {
  __shared__ alignas(16) bf16 PA[2][2][128 * 32];
  __shared__ alignas(16) bf16 PB[2][2][128 * 32];
  const int tid = threadIdx.x, wave = tid >> 6, lane = tid & 63;
  const int quad = lane >> 4, l16 = lane & 15;
  const int rowBlk = blockIdx.x * 128, colBlk = blockIdx.y * 128;
  const int wr = wave >> 1, wc = wave & 1;
  const int srow = lane >> 2;
  const int skel = (((lane & 3) ^ ((lane >> 3) & 3)) * 8);
  const int qsw = quad ^ ((l16 >> 1) & 3);

  const bf16* gA0 = A + (size_t)(rowBlk + wave * 32 + srow) * lda + skel;
  const bf16* gA1 = gA0 + (size_t)16 * lda;
  const bf16* gB0 = Bt + (size_t)(colBlk + wave * 32 + srow) * K + skel;
  const bf16* gB1 = gB0 + (size_t)16 * K;

#define STG128(t, b)                                      \
  do {                                                    \
    const int k0_ = (t)*64;                               \
    gld_lds16(gA0 + k0_, &PA[b][0][wave * 1024]);         \
    gld_lds16(gA1 + k0_, &PA[b][0][wave * 1024 + 512]);   \
    gld_lds16(gA0 + k0_ + 32, &PA[b][1][wave * 1024]);    \
    gld_lds16(gA1 + k0_ + 32, &PA[b][1][wave * 1024 + 512]); \
    gld_lds16(gB0 + k0_, &PB[b][0][wave * 1024]);         \
    gld_lds16(gB1 + k0_, &PB[b][0][wave * 1024 + 512]);   \
    gld_lds16(gB0 + k0_ + 32, &PB[b][1][wave * 1024]);    \
    gld_lds16(gB1 + k0_ + 32, &PB[b][1][wave * 1024 + 512]); \
  } while (0)

  f32x4 acc[4][4] = {};
  const int nt = K >> 6;
  STG128(0, 0);
  STG128(1, 1);
  VMCNT(8);
  SBAR();
  SCHED0();
  for (int t = 0; t < nt; ++t) {
    const int b = t & 1;
#pragma unroll
    for (int ks = 0; ks < 2; ++ks) {
      const bf16* aRd = &PA[b][ks][(wr * 64 + l16) * 32 + qsw * 8];
      const bf16* bRd = &PB[b][ks][(wc * 64 + l16) * 32 + qsw * 8];
      bf16x8 af[4], bfr[4];
#pragma unroll
      for (int i = 0; i < 4; ++i) {
        af[i] = *(const bf16x8*)(aRd + i * 16 * 32);
        bfr[i] = *(const bf16x8*)(bRd + i * 16 * 32);
      }
#pragma unroll
      for (int mi = 0; mi < 4; ++mi)
#pragma unroll
        for (int ni = 0; ni < 4; ++ni)
          acc[mi][ni] = MFMA16(bfr[ni], af[mi], acc[mi][ni]);
    }
    if (t == nt - 1) break;
    SBAR();  // all waves done reading buf b
    SCHED0();
    if (t + 2 < nt) {
      STG128(t + 2, b);
      VMCNT(8);
    } else {
      VMCNT(0);
    }
    SBAR();  // buf b^1 ready
    SCHED0();
  }
#undef STG128

  const bool doAct = (colBlk < act_cols);
  bf16* const Cp = doAct ? C1 : C2;
  const int cShift = doAct ? 0 : act_cols;
#pragma unroll
  for (int mi = 0; mi < 4; ++mi) {
    const int row = rowBlk + wr * 64 + mi * 16 + l16;
#pragma unroll
    for (int ni = 0; ni < 4; ++ni) {
      const int col0 = colBlk + wc * 64 + ni * 16 + quad * 4;
      const f32x4 bb = *(const f32x4*)(bias + col0);
      bf16x4 o;
#pragma unroll
      for (int r = 0; r < 4; ++r) {
        float x = acc[mi][ni][r] + bb[r];
        if (doAct) x = silu(x);
        o[r] = (bf16)x;
      }
      *(bf16x4*)(Cp + (size_t)row * ldc + (col0 - cShift)) = o;
    }
  }
}

// ---- per-step trunk: [policy-L1 | dyn-L1z | value-L1] in one GEMM -----
// K=256, N=3072, grid (128,24) = 3072 blocks, single-buf 32KB (5/CU).
// FINAL: sbuf128 beat dbuf128/sbuf256/8phase/persistent-B (R12-R17).
__global__ __launch_bounds__(256) void gemm_pd1v(
    const bf16* __restrict__ A, const bf16* __restrict__ Bt,
    const float* __restrict__ pdb1, const float* __restrict__ vbiasT,
    bf16* __restrict__ Ha, bf16* __restrict__ Hp, bf16* __restrict__ Hv) {
  __shared__ alignas(16) bf16 As0[128 * 32], As1[128 * 32];
  __shared__ alignas(16) bf16 Bs0[128 * 32], Bs1[128 * 32];
  const int tid = threadIdx.x, wave = tid >> 6, lane = tid & 63;
  const int quad = lane >> 4, l16 = lane & 15;
  const int rowBlk = blockIdx.x * 128, colBlk = blockIdx.y * 128;
  const int wr = wave >> 1, wc = wave & 1;
  const int srow = lane >> 2;
  const int skel = (((lane & 3) ^ ((lane >> 3) & 3)) * 8);
  const int qsw = quad ^ ((l16 >> 1) & 3);

  const bf16* gA0 = A + (size_t)(rowBlk + wave * 32 + srow) * 256 + skel;
  const bf16* gA1 = gA0 + (size_t)16 * 256;
  const bf16* gB0 = Bt + (size_t)(colBlk + wave * 32 + srow) * 256 + skel;
  const bf16* gB1 = gB0 + (size_t)16 * 256;
  bf16* const lA0 = As0 + wave * 32 * 32;
  bf16* const lA0b = As0 + (wave * 32 + 16) * 32;
  bf16* const lA1 = As1 + wave * 32 * 32;
  bf16* const lA1b = As1 + (wave * 32 + 16) * 32;
  bf16* const lB0 = Bs0 + wave * 32 * 32;
  bf16* const lB0b = Bs0 + (wave * 32 + 16) * 32;
  bf16* const lB1 = Bs1 + wave * 32 * 32;
  bf16* const lB1b = Bs1 + (wave * 32 + 16) * 32;

  f32x4 acc[4][4] = {};
  for (int k0 = 0; k0 < 256; k0 += 64) {
    gld_lds16(gA0 + k0, lA0);
    gld_lds16(gA1 + k0, lA0b);
    gld_lds16(gA0 + k0 + 32, lA1);
    gld_lds16(gA1 + k0 + 32, lA1b);
    gld_lds16(gB0 + k0, lB0);
    gld_lds16(gB1 + k0, lB0b);
    gld_lds16(gB0 + k0 + 32, lB1);
    gld_lds16(gB1 + k0 + 32, lB1b);
    __syncthreads();
#pragma unroll
    for (int ks = 0; ks < 2; ++ks) {
      const bf16* aRd = (ks ? As1 : As0) + (wr * 64 + l16) * 32 + qsw * 8;
      const bf16* bRd = (ks ? Bs1 : Bs0) + (wc * 64 + l16) * 32 + qsw * 8;
      bf16x8 af[4], bfr[4];
#pragma unroll
      for (int i = 0; i < 4; ++i) {
        af[i] = *(const bf16x8*)(aRd + i * 16 * 32);
        bfr[i] = *(const bf16x8*)(bRd + i * 16 * 32);
      }
#pragma unroll
      for (int mi = 0; mi < 4; ++mi)
#pragma unroll
        for (int ni = 0; ni < 4; ++ni)
          acc[mi][ni] = MFMA16(bfr[ni], af[mi], acc[mi][ni]);
    }
    __syncthreads();
  }

  const int seg = colBlk >> 10;  // 0: policy, 1: dyn-z (linear), 2: value
  bf16* const Cp = (seg == 0) ? Ha : (seg == 1) ? Hp : Hv;
  const int cShift = seg << 10;
  const float* const bp = (seg == 2) ? (vbiasT - 2048) : pdb1;
#pragma unroll
  for (int mi = 0; mi < 4; ++mi) {
    const int row = rowBlk + wr * 64 + mi * 16 + l16;
#pragma unroll
    for (int ni = 0; ni < 4; ++ni) {
      const int col0 = colBlk + wc * 64 + ni * 16 + quad * 4;
      const f32x4 bb = *(const f32x4*)(bp + col0);
      bf16x4 o;
#pragma unroll
      for (int r = 0; r < 4; ++r) {
        float x = acc[mi][ni][r] + bb[r];
        if (seg != 1) x = silu(x);
        o[r] = (bf16)x;
      }
      *(bf16x4*)(Cp + (size_t)row * 1024 + (col0 - cShift)) = o;
    }
  }
}

// ---- 256x256 8-phase GEMM body (shared by gemm256 and gemm256_dual) ---
template <int NT, int EPI>
__device__ __forceinline__ void gemm256_body(
    const bf16* __restrict__ A, const bf16* __restrict__ Bt, int rowBlk,
    int colBlk, const float* __restrict__ bias, const float* __restrict__ aux,
    bf16* __restrict__ C1, float* __restrict__ efe, float disc,
    bf16 (*sAB)[2][256 * 64]) {
  constexpr int K = NT * 64;
  const int tid = threadIdx.x, wave = tid >> 6, lane = tid & 63;
  const int quad = lane >> 4, l16 = lane & 15;
  const int wr = wave >> 2, wc = wave & 3;  // 2 x 4 wave grid

  const int j8 = lane >> 3;
  const int c16e = ((lane & 7) ^ j8) * 8;  // inverse-swizzled source col
  const bf16* gAs = A + (size_t)(rowBlk + wave * 16 + j8) * K + c16e;
  const bf16* gBs = Bt + (size_t)(colBlk + wave * 16 + j8) * K + c16e;

#define STAGE_A(hh, tt, bb)                                           \
  do {                                                                \
    const bf16* g_ = gAs + (hh) * 128 * K + (tt) * 64;                \
    bf16* l_ = &sAB[(bb)][0][((hh) * 128 + wave * 16) * 64];          \
    gld_lds16(g_, l_);                                                \
    gld_lds16(g_ + 8 * K, l_ + 8 * 64);                               \
  } while (0)
#define STAGE_B(hh, tt, bb)                                           \
  do {                                                                \
    const bf16* g_ = gBs + (hh) * 128 * K + (tt) * 64;                \
    bf16* l_ = &sAB[(bb)][1][((hh) * 128 + wave * 16) * 64];          \
    gld_lds16(g_, l_);                                                \
    gld_lds16(g_ + 8 * K, l_ + 8 * 64);                               \
  } while (0)

  const int k0x = (quad * 8) ^ ((l16 & 7) << 3);
  const int aOff = (wr * 128 + l16) * 64 + k0x;
  const int bOff = (wc * 64 + l16) * 64 + k0x;

  bf16x8 bAf[4][2], bBf[2][2], bB2f[2][2];
  f32x4 acc[8][4] = {};

  // prologue: tile0 fully + tile1 B-halves
  STAGE_A(0, 0, 0);
  STAGE_A(1, 0, 0);
  STAGE_B(0, 0, 0);
  STAGE_B(1, 0, 0);
  STAGE_B(0, 1, 1);
  STAGE_B(1, 1, 1);
  VMCNT(4);
  SBAR();
  SCHED0();

#pragma unroll 2
  for (int t = 0; t < NT; ++t) {
    const int buf = t & 1;
    const bf16* lA = &sAB[buf][0][0];
    const bf16* lB = &sAB[buf][1][0];

    // q0: read A m0-3 + B n0-1; stage A0(t+1); MFMA q0
#pragma unroll
    for (int m = 0; m < 4; ++m)
#pragma unroll
      for (int ks = 0; ks < 2; ++ks)
        bAf[m][ks] = *(const bf16x8*)(lA + ((aOff + m * 1024) ^ (ks << 5)));
#pragma unroll
    for (int n = 0; n < 2; ++n)
#pragma unroll
      for (int ks = 0; ks < 2; ++ks)
        bBf[n][ks] = *(const bf16x8*)(lB + ((bOff + n * 1024) ^ (ks << 5)));
    if (t + 1 < NT) STAGE_A(0, t + 1, buf ^ 1);
    SBAR();
    LGKMCNT0();
    SCHED0();
    __builtin_amdgcn_s_setprio(1);
#pragma unroll
    for (int ks = 0; ks < 2; ++ks)
#pragma unroll
      for (int m = 0; m < 4; ++m)
#pragma unroll
        for (int n = 0; n < 2; ++n)
          acc[m][n] = MFMA16(bBf[n][ks], bAf[m][ks], acc[m][n]);
    __builtin_amdgcn_s_setprio(0);
    SBAR();
    SCHED0();

    // q1: read B n2-3; stage A1(t+1); MFMA m0-3 x n2-3
#pragma unroll
    for (int n = 0; n < 2; ++n)
#pragma unroll
      for (int ks = 0; ks < 2; ++ks)
        bB2f[n][ks] =
            *(const bf16x8*)(lB + ((bOff + (n + 2) * 1024) ^ (ks << 5)));
    if (t + 1 < NT) STAGE_A(1, t + 1, buf ^ 1);
    SBAR();
    LGKMCNT0();
    SCHED0();
    __builtin_amdgcn_s_setprio(1);
#pragma unroll
    for (int ks = 0; ks < 2; ++ks)
#pragma unroll
      for (int m = 0; m < 4; ++m)
#pragma unroll
        for (int n = 0; n < 2; ++n)
          acc[m][n + 2] = MFMA16(bB2f[n][ks], bAf[m][ks], acc[m][n + 2]);
    __builtin_amdgcn_s_setprio(0);
    SBAR();
    SCHED0();

    // q2: read A m4-7; stage B0(t+2); MFMA m4-7 x n2-3
#pragma unroll
    for (int m = 0; m < 4; ++m)
#pragma unroll
      for (int ks = 0; ks < 2; ++ks)
        bAf[m][ks] =
            *(const bf16x8*)(lA + ((aOff + (m + 4) * 1024) ^ (ks << 5)));
    if (t + 2 < NT) STAGE_B(0, t + 2, buf);
    SBAR();
    LGKMCNT0();
    SCHED0();
    __builtin_amdgcn_s_setprio(1);
#pragma unroll
    for (int ks = 0; ks < 2; ++ks)
#pragma unroll
      for (int m = 0; m < 4; ++m)
#pragma unroll
        for (int n = 0; n < 2; ++n)
          acc[m + 4][n + 2] =
              MFMA16(bB2f[n][ks], bAf[m][ks], acc[m + 4][n + 2]);
    __builtin_amdgcn_s_setprio(0);
    SBAR();
    SCHED0();

    // q3: no reads; stage B1(t+2); MFMA m4-7 x n0-1; counted vmcnt
    if (t + 2 < NT) STAGE_B(1, t + 2, buf);
    SBAR();
    SCHED0();
    __builtin_amdgcn_s_setprio(1);
#pragma unroll
    for (int ks = 0; ks < 2; ++ks)
#pragma unroll
      for (int m = 0; m < 4; ++m)
#pragma unroll
        for (int n = 0; n < 2; ++n)
          acc[m + 4][n] = MFMA16(bBf[n][ks], bAf[m][ks], acc[m + 4][n]);
    __builtin_amdgcn_s_setprio(0);
    if (t < NT - 2) {
      VMCNT(4);
    } else {
      VMCNT(0);
    }
    SBAR();
    SCHED0();
  }
#undef STAGE_A
#undef STAGE_B

  if constexpr (EPI == 0) {  // silu(acc + bias) -> C1, ldc=1024
#pragma unroll
    for (int m = 0; m < 8; ++m) {
      const int row = rowBlk + wr * 128 + m * 16 + l16;
#pragma unroll
      for (int n = 0; n < 4; ++n) {
        const int gcol = colBlk + wc * 64 + n * 16 + quad * 4;
        const f32x4 bb = *(const f32x4*)(bias + gcol);
        bf16x4 o;
#pragma unroll
        for (int r = 0; r < 4; ++r) o[r] = (bf16)silu(acc[m][n][r] + bb[r]);
        *(bf16x4*)(C1 + (size_t)row * 1024 + gcol) = o;
      }
    }
  } else {  // EPI == 1: value L2 + vW3 dot -> efe
#pragma unroll
    for (int m = 0; m < 8; ++m) {
      const int row = rowBlk + wr * 128 + m * 16 + l16;
      float p = 0.f;
#pragma unroll
      for (int n = 0; n < 4; ++n) {
        const int gcol = colBlk + wc * 64 + n * 16 + quad * 4;
        const f32x4 bb = *(const f32x4*)(bias + gcol);
        const f32x4 w3 = *(const f32x4*)(aux + gcol);
#pragma unroll
        for (int r = 0; r < 4; ++r) p += silu(acc[m][n][r] + bb[r]) * w3[r];
      }
      p += __shfl_xor(p, 16);
      p += __shfl_xor(p, 32);
      if (quad == 0) atomicAdd(efe + row, disc * p);
    }
  }
}

template <int NT, int EPI>
__global__ __launch_bounds__(512, 2) void gemm256(
    const bf16* __restrict__ A, const bf16* __restrict__ Bt, int nCol,
    const float* __restrict__ bias, const float* __restrict__ aux,
    bf16* __restrict__ C1, float* __restrict__ efe, float disc) {
  static_assert(NT >= 2, "need at least 2 K-tiles");
  __shared__ alignas(16) bf16 sAB[2][2][256 * 64];
  const int nwg = gridDim.x, flat = blockIdx.x;
  const int lid = (flat & 7) * (nwg >> 3) + (flat >> 3);
  const int rowBlk = (lid / nCol) * 256, colBlk = (lid % nCol) * 256;
  gemm256_body<NT, EPI>(A, Bt, rowBlk, colBlk, bias, aux, C1, efe, disc, sAB);
}

// fused {policy-L2 (EPI0), value-L2+dot (EPI1)}: grid 256, TEMPORAL.
template <int NT>
__global__ __launch_bounds__(512, 2) void gemm256_dual(
    const bf16* __restrict__ A0, const bf16* __restrict__ Bt0,
    const float* __restrict__ bias0, bf16* __restrict__ C0,
    const bf16* __restrict__ A1, const bf16* __restrict__ Bt1,
    const float* __restrict__ bias1, const float* __restrict__ aux1,
    float* __restrict__ efe, float disc) {
  __shared__ alignas(16) bf16 sAB[2][2][256 * 64];
  const int flat = blockIdx.x;  // 256 blocks
  const int seq = (flat & 7) * 32 + (flat >> 3);  // 0..255, XCD-chunked
  const int rowBlk = (seq >> 2) * 256, colBlk = (seq & 3) * 256;
  gemm256_body<NT, 0>(A0, Bt0, rowBlk, colBlk, bias0, nullptr, C0, nullptr,
                      0.f, sAB);
  gemm256_body<NT, 1>(A1, Bt1, rowBlk, colBlk, bias1, aux1, nullptr, efe,
                      disc, sAB);
}

// ---- dynamics L3 + z_next + KL partials fused -------------------------
// dbuf + counted vmcnt (6 loads/thread per stage), K=1024 (nt=16).
// R16 form: 2-col split, 48KB LDS, grid (256,2) - col-fusion regressed.
__global__ __launch_bounds__(256) void gemm_dyn3(
    const bf16* __restrict__ A, const bf16* __restrict__ Bt,
    const float* __restrict__ db3, float* __restrict__ Zf,
    bf16* __restrict__ Zb, float* __restrict__ s_n, float* __restrict__ s_c) {
  __shared__ alignas(16) bf16 PA[2][2][64 * 32];
  __shared__ alignas(16) bf16 PB[2][2][128 * 32];
  const int tid = threadIdx.x, wave = tid >> 6, lane = tid & 63;
  const int quad = lane >> 4, l16 = lane & 15;
  const int rowBlk = blockIdx.x * 64, colBlk = blockIdx.y * 128;
  const int srow = lane >> 2;
  const int skel = (((lane & 3) ^ ((lane >> 3) & 3)) * 8);
  const int qsw = quad ^ ((l16 >> 1) & 3);

  const bf16* gA = A + (size_t)(rowBlk + wave * 16 + srow) * 1024 + skel;
  const bf16* gB0 = Bt + (size_t)(colBlk + wave * 32 + srow) * 1024 + skel;
  const bf16* gB1 = gB0 + (size_t)16 * 1024;

#define STGD(t, b)                                        \
  do {                                                    \
    const int k0_ = (t)*64;                               \
    gld_lds16(gA + k0_, &PA[b][0][wave * 512]);           \
    gld_lds16(gA + k0_ + 32, &PA[b][1][wave * 512]);      \
    gld_lds16(gB0 + k0_, &PB[b][0][wave * 1024]);         \
    gld_lds16(gB1 + k0_, &PB[b][0][wave * 1024 + 512]);   \
    gld_lds16(gB0 + k0_ + 32, &PB[b][1][wave * 1024]);    \
    gld_lds16(gB1 + k0_ + 32, &PB[b][1][wave * 1024 + 512]); \
  } while (0)

  f32x4 acc[8] = {};
  STGD(0, 0);
  STGD(1, 1);
  VMCNT(6);
  SBAR();
  SCHED0();
#pragma unroll 2
  for (int t = 0; t < 16; ++t) {
    const int b = t & 1;
#pragma unroll
    for (int ks = 0; ks < 2; ++ks) {
      const bf16* aRd = &PA[b][ks][(wave * 16 + l16) * 32 + qsw * 8];
      const bf16* bRd = &PB[b][ks][l16 * 32 + qsw * 8];
      const bf16x8 af = *(const bf16x8*)aRd;
#pragma unroll
      for (int ni = 0; ni < 8; ++ni) {
        const bf16x8 bfr = *(const bf16x8*)(bRd + ni * 16 * 32);
        acc[ni] = MFMA16(bfr, af, acc[ni]);
      }
    }
    if (t == 15) break;
    SBAR();
    SCHED0();
    if (t < 14) {
      STGD(t + 2, b);
      VMCNT(6);
    } else {
      VMCNT(0);
    }
    SBAR();
    SCHED0();
  }
#undef STGD

  const int row = rowBlk + wave * 16 + l16;
  float pn = 0.f, pc = 0.f;
#pragma unroll
  for (int ni = 0; ni < 8; ++ni) {
    const int col0 = colBlk + ni * 16 + quad * 4;
    const f32x4 b4 = *(const f32x4*)(db3 + col0);
    float* zp = Zf + (size_t)row * 256 + col0;
    const f32x4 z = *(const f32x4*)zp;
    f32x4 zn;
    bf16x4 o;
#pragma unroll
    for (int r = 0; r < 4; ++r) {
      zn[r] = z[r] + acc[ni][r] + b4[r];
      pn += zn[r] * zn[r];
      pc += z[r] * zn[r];
      o[r] = (bf16)zn[r];
    }
    *(f32x4*)zp = zn;
    *(bf16x4*)(Zb + (size_t)row * 256 + col0) = o;
  }
  pn += __shfl_xor(pn, 16);
  pn += __shfl_xor(pn, 32);
  pc += __shfl_xor(pc, 16);
  pc += __shfl_xor(pc, 32);
  if (quad == 0) {
    atomicAdd(s_n + row, pn);
    atomicAdd(s_c + row, pc);
  }
}

// ---- batched KL epilogue: all 5 steps at once -------------------------
__global__ void kl_batch(const float* __restrict__ sz0,
                         const float* __restrict__ snAll,
                         const float* __restrict__ scAll,
                         float* __restrict__ efe) {
  const int m = blockIdx.x * 256 + threadIdx.x;
  float sz = sz0[m];
  float disc = 1.f, acc = 0.f;
  for (int t = 0; t < HORIZON; ++t) {
    const float sn = snAll[t * MR + m], sc = scAll[t * MR + m];
    const float nz = sqrtf(sz) + 1e-8f, nn = sqrtf(sn) + 1e-8f;
    const float kl =
        0.5f * (sz / (nz * nz) + sn / (nn * nn) - 2.f * sc / (nz * nn));
    acc += disc * log1pf(fmaxf(kl, 0.f));
    sz = sn;
    disc *= 0.99f;
  }
  efe[m] += acc;
}

// ---- heads4: split-K heads + dynamics-L1 completion -------------------
// Per-wave panels (wave owns K-quarter) -> NO barriers in k-loop; per-wave
// dbuf + counted VMCNT(5) keeps one tile in flight while computing.
__global__ __launch_bounds__(256) void heads4(
    const bf16* __restrict__ H, const bf16* __restrict__ Wt,
    const float* __restrict__ pbm, const float* __restrict__ pbs,
    const float* __restrict__ noise, const bf16* __restrict__ preD,
    const bf16* __restrict__ dW1at, bf16* __restrict__ Hd,
    float* __restrict__ efe, int t, float disc, int rmask) {
  __shared__ alignas(16) bf16 As[2][4 * 16 * 32];
  __shared__ alignas(16) bf16 Bs[2][4 * 64 * 32];  // Bs[0] aliased as f32 red
  __shared__ alignas(16) bf16 LAct[16 * 32];
  const int tid = threadIdx.x, wave = tid >> 6, lane = tid & 63;
  const int quad = lane >> 4, l16 = lane & 15;
  const int rowBlk = blockIdx.x * 16;
  const int srow = lane >> 2;
  const int skel = (((lane & 3) ^ ((lane >> 3) & 3)) * 8);
  const int qsw = quad ^ ((l16 >> 1) & 3);
  const int kw = wave * 256;

  const bf16* gA = H + (size_t)((rowBlk + srow) & rmask) * 1024 + kw + skel;

#define STGH(kt, b)                                                         \
  do {                                                                      \
    gld_lds16(gA + (kt) * 32, &As[b][wave * 512]);                          \
    _Pragma("unroll") for (int j = 0; j < 4; ++j) gld_lds16(                \
        Wt + (size_t)(j * 16 + srow) * 1024 + kw + (kt) * 32 + skel,        \
        &Bs[b][wave * 2048 + j * 512]);                                     \
  } while (0)

  f32x4 acc[4] = {};
  STGH(0, 0);
  STGH(1, 1);  // 10 loads in flight
#pragma unroll
  for (int kt = 0; kt < 8; ++kt) {
    const int b = kt & 1;
    if (kt < 7) {
      VMCNT(5);  // tile kt landed; tile kt+1 stays in flight
    } else {
      VMCNT(0);
    }
    SCHED0();
    const bf16x8 af =
        *(const bf16x8*)(&As[b][wave * 512] + l16 * 32 + qsw * 8);
#pragma unroll
    for (int ni = 0; ni < 4; ++ni) {
      const bf16x8 bfr =
          *(const bf16x8*)(&Bs[b][wave * 2048] + (ni * 16 + l16) * 32 + qsw * 8);
      acc[ni] = MFMA16(bfr, af, acc[ni]);
    }
    SCHED0();  // pin: ds_reads/MFMA above, restage below
    if (kt < 6) {
      LGKMCNT0();  // ds_reads of buf b fully retired before overwrite
      STGH(kt + 2, b);
    }
  }
#undef STGH

  // cross-wave reduction: partials through Bs[0]-aliased f32 scratch
  float* red = (float*)Bs;  // wave w's slice aliases its OWN Bs[0] panel
#pragma unroll
  for (int ni = 0; ni < 4; ++ni)
    *(f32x4*)(red + wave * 1024 + ni * 256 + lane * 4) = acc[ni];
  __syncthreads();
#pragma unroll
  for (int ni = 0; ni < 4; ++ni) {
    f32x4 s = *(const f32x4*)(red + ni * 256 + lane * 4);
#pragma unroll
    for (int w2 = 1; w2 < 4; ++w2) {
      const f32x4 p = *(const f32x4*)(red + w2 * 1024 + ni * 256 + lane * 4);
#pragma unroll
      for (int r = 0; r < 4; ++r) s[r] += p[r];
    }
    acc[ni] = s;
  }

  // action + entropy (computed redundantly by all waves; wave0 writes)
  const int row = rowBlk + l16;
  const int n = row >> 10, b2 = row & 1023;
  float ent = 0.f;
#pragma unroll
  for (int ni = 0; ni < 2; ++ni) {
    const int col0 = ni * 16 + quad * 4;
    const f32x4 bm4 = *(const f32x4*)(pbm + col0);
    const f32x4 bs4 = *(const f32x4*)(pbs + col0);
    const f32x4 ep4 =
        *(const f32x4*)(noise + (((size_t)(n * 5 + t) * 1024 + b2) * 32 + col0));
    bf16x4 o;
#pragma unroll
    for (int r = 0; r < 4; ++r) {
      const float mean = acc[ni][r] + bm4[r];
      float ls = acc[ni + 2][r] + bs4[r];
      ls = fminf(fmaxf(ls, -5.f), 2.f);
      o[r] = (bf16)(mean + __expf(ls) * ep4[r]);
      ent += ENT_C + ls;
    }
    if (wave == 0) *(bf16x4*)(LAct + l16 * 32 + col0) = o;
  }
  ent += __shfl_xor(ent, 16);
  ent += __shfl_xor(ent, 32);
  if (wave == 0 && quad == 0) efe[row] += disc * (-0.1f) * ent;
  __syncthreads();  // LAct ready

  // rank-32 completion: wave w handles col-tiles [w*16, w*16+16)
  const int prow = row & rmask;
  const bf16x8 af2 = *(const bf16x8*)(LAct + l16 * 32 + quad * 8);
#pragma unroll 4
  for (int ci = 0; ci < 16; ++ci) {
    const int ct = wave * 16 + ci;
    const bf16x8 wf =
        *(const bf16x8*)(dW1at + (size_t)(ct * 16 + l16) * 32 + quad * 8);
    f32x4 a = {};
    a = MFMA16(wf, af2, a);
    const int col0 = ct * 16 + quad * 4;
    const bf16x4 pd = *(const bf16x4*)(preD + (size_t)prow * 1024 + col0);
    bf16x4 o;
#pragma unroll
    for (int r = 0; r < 4; ++r) o[r] = (bf16)silu(a[r] + (float)pd[r]);
    *(bf16x4*)(Hd + (size_t)row * 1024 + col0) = o;
  }
}

// ---- unified prep: coalesced tiled transposes + vbias + init ----------
__global__ __launch_bounds__(256) void prep_tr(
    const float* __restrict__ pW1, const float* __restrict__ dW1,
    const float* __restrict__ vW1, const float* __restrict__ pW2,
    const float* __restrict__ dW2, const float* __restrict__ dW3,
    const float* __restrict__ vW2, const float* __restrict__ pWm,
    const float* __restrict__ pWs, const float* __restrict__ pb1,
    const float* __restrict__ db1, const float* __restrict__ vb1,
    const float* __restrict__ latent, bf16* __restrict__ pdW1vt,
    bf16* __restrict__ pW2t, bf16* __restrict__ pHt,
    bf16* __restrict__ dW1at, bf16* __restrict__ dW2t,
    bf16* __restrict__ dW3t, bf16* __restrict__ vW2t,
    float* __restrict__ pdb1, float* __restrict__ vbias,
    float* __restrict__ Zf, bf16* __restrict__ Zb0, float* __restrict__ efe,
    float* __restrict__ sz0, float* __restrict__ snAll,
    float* __restrict__ scAll) {
  int bid = blockIdx.x;
  if (bid == 1072) {  // pdb1
    for (int i = threadIdx.x; i < 2048; i += 256)
      pdb1[i] = (i < 1024) ? pb1[i] : db1[i - 1024];
    return;
  }
  if (bid >= 1073 && bid < 1093) {  // vbias
    const int idx = (bid - 1073) * 256 + threadIdx.x;  // < 5120
    const int t = idx >> 10, j = idx & 1023;
    float s = vb1[j];
    const float lt = (float)t;
    for (int i = 0; i < 64; ++i) {
      const float f = expf(-9.210340371976184f * (float)i / 64.f);
      const float ang = lt * f;
      s += sinf(ang) * vW1[(size_t)(256 + i) * 1024 + j];
      s += cosf(ang) * vW1[(size_t)(256 + 64 + i) * 1024 + j];
    }
    vbias[idx] = s;
    return;
  }
  if (bid >= 1093) {  // init: 4 rows/block, wave per row
    const int wave = threadIdx.x >> 6, lane = threadIdx.x & 63;
    const int row = (bid - 1093) * 4 + wave;
    const f32x4 z = *(const f32x4*)(latent + (size_t)(row & 1023) * 256 + lane * 4);
    *(f32x4*)(Zf + (size_t)row * 256 + lane * 4) = z;
    if (row < 1024) {
      bf16x4 o = {(bf16)z[0], (bf16)z[1], (bf16)z[2], (bf16)z[3]};
      *(bf16x4*)(Zb0 + (size_t)row * 256 + lane * 4) = o;
    }
    float s = z[0] * z[0] + z[1] * z[1] + z[2] * z[2] + z[3] * z[3];
#pragma unroll
    for (int m = 1; m < 64; m <<= 1) s += __shfl_xor(s, m);
    if (lane == 0) {
      sz0[row] = s;
      efe[row] = 0.f;
    }
    if (lane < HORIZON) {
      snAll[lane * MR + row] = 0.f;
      scAll[lane * MR + row] = 0.f;
    }
    return;
  }
  // ---- tiled transpose segments ----
  const float* in;
  bf16* out;
  int K, N, ldin, ro = 0;
  if (bid < 64) { in = pW1; out = pdW1vt; K = 256; N = 1024; ldin = 1024; }
  else if (bid < 128) { bid -= 64; in = dW1; out = pdW1vt + 1024 * 256; K = 256; N = 1024; ldin = 1024; }
  else if (bid < 192) { bid -= 128; in = vW1; out = pdW1vt + 2048 * 256; K = 256; N = 1024; ldin = 1024; }
  else if (bid < 448) { bid -= 192; in = pW2; out = pW2t; K = 1024; N = 1024; ldin = 1024; }
  else if (bid < 704) { bid -= 448; in = dW2; out = dW2t; K = 1024; N = 1024; ldin = 1024; }
  else if (bid < 960) { bid -= 704; in = vW2; out = vW2t; K = 1024; N = 1024; ldin = 1024; }
  else if (bid < 1024) { bid -= 960; in = dW3; out = dW3t; K = 1024; N = 256; ldin = 256; }
  else if (bid < 1040) { bid -= 1024; in = dW1; out = dW1at; K = 32; N = 1024; ldin = 1024; ro = 256; }
  else if (bid < 1056) { bid -= 1040; in = pWm; out = pHt; K = 1024; N = 32; ldin = 32; }
  else { bid -= 1056; in = pWs; out = pHt + 32 * 1024; K = 1024; N = 32; ldin = 32; }

  const int ktiles = (K + 63) >> 6;
  const int k0 = (bid % ktiles) * 64, n0 = (bid / ktiles) * 64;
  __shared__ float tile[64][65];
  const int tx = threadIdx.x & 63, ty = threadIdx.x >> 6;
#pragma unroll
  for (int i = 0; i < 16; ++i) {
    const int k = k0 + ty + i * 4;
    if (k < K && n0 + tx < N)
      tile[ty + i * 4][tx] = in[(size_t)(ro + k) * ldin + n0 + tx];
  }
  __syncthreads();
#pragma unroll
  for (int i = 0; i < 16; ++i) {
    const int n = n0 + ty + i * 4;
    if (n < N && k0 + tx < K)
      out[(size_t)n * K + k0 + tx] = (bf16)tile[tx][ty + i * 4];
  }
}

__global__ void finalize(const float* __restrict__ efe,
                         const float* __restrict__ vb3,
                         float* __restrict__ out) {
  const int b = blockIdx.x * 256 + threadIdx.x;  // 1024
  float s = 0.f;
#pragma unroll
  for (int n = 0; n < 16; ++n) s += efe[n * 1024 + b];
  out[b] = s * (1.f / 16.f) + SUMDISC * vb3[0];
}

extern "C" void kernel_launch(void* const* d_in, const int* in_sizes, int n_in,
                              void* d_out, int out_size, void* d_ws,
                              size_t ws_size, hipStream_t stream) {
  const float* latent = (const float*)d_in[0];
  const float* noise = (const float*)d_in[1];
  const float* pW1 = (const float*)d_in[2];
  const float* pb1 = (const float*)d_in[3];
  const float* pW2 = (const float*)d_in[4];
  const float* pb2 = (const float*)d_in[5];
  const float* pWm = (const float*)d_in[6];
  const float* pbm = (const float*)d_in[7];
  const float* pWs = (const float*)d_in[8];
  const float* pbs = (const float*)d_in[9];
  const float* dW1 = (const float*)d_in[10];
  const float* db1 = (const float*)d_in[11];
  const float* dW2 = (const float*)d_in[12];
  const float* db2 = (const float*)d_in[13];
  const float* dW3 = (const float*)d_in[14];
  const float* db3 = (const float*)d_in[15];
  const float* vW1 = (const float*)d_in[16];
  const float* vb1 = (const float*)d_in[17];
  const float* vW2 = (const float*)d_in[18];
  const float* vb2 = (const float*)d_in[19];
  const float* vW3 = (const float*)d_in[20];
  const float* vb3 = (const float*)d_in[21];

  char* w = (char*)d_ws;
  size_t off = 0;
  auto take = [&](size_t bytes) -> void* {
    void* p = (void*)(w + off);
    off = (off + bytes + 255) & ~(size_t)255;
    return p;
  };
  bf16* pdW1vt = (bf16*)take(3072ull * 256 * 2);  // [pW1|dW1z|vW1]^T
  float* pdb1 = (float*)take(2048ull * 4);
  bf16* pW2t = (bf16*)take(1024ull * 1024 * 2);
  bf16* pHt = (bf16*)take(64ull * 1024 * 2);
  bf16* dW1at = (bf16*)take(1024ull * 32 * 2);
  bf16* dW2t = (bf16*)take(1024ull * 1024 * 2);
  bf16* dW3t = (bf16*)take(256ull * 1024 * 2);
  bf16* vW2t = (bf16*)take(1024ull * 1024 * 2);
  float* vbias = (float*)take(5ull * 1024 * 4);
  bf16* Zb0 = (bf16*)take(1024ull * 256 * 2);      // z0 bf16, shared rows
  bf16* Zb = (bf16*)take((size_t)MR * 256 * 2);    // z_t bf16 (single buf)
  float* Zf = (float*)take((size_t)MR * 256 * 4);  // fp32 master z
  float* efe = (float*)take((size_t)MR * 4);
  float* sz0 = (float*)take((size_t)MR * 4);
  float* snAll = (float*)take(5ull * MR * 4);
  float* scAll = (float*)take(5ull * MR * 4);
  bf16* Ha = (bf16*)take((size_t)MR * 1024 * 2);
  bf16* Hc = (bf16*)take((size_t)MR * 1024 * 2);
  bf16* Hp = (bf16*)take((size_t)MR * 1024 * 2);
  bf16* Hv = (bf16*)take((size_t)MR * 1024 * 2);
  bf16* vW1t = pdW1vt + (size_t)2048 * 256;  // value-L1 weights (tail step)

  const dim3 blk(256), blk2(512);
  const int BIG = 1 << 30;
  // prep_tr: 1072 transpose tiles + pdb1 + 20 vbias + 4096 init blocks
  prep_tr<<<dim3(1093 + MR / 4), blk, 0, stream>>>(
      pW1, dW1, vW1, pW2, dW2, dW3, vW2, pWm, pWs, pb1, db1, vb1, latent,
      pdW1vt, pW2t, pHt, dW1at, dW2t, dW3t, vW2t, pdb1, vbias, Zf, Zb0, efe,
      sz0, snAll, scAll);

  float disc = 1.f, dprev = 1.f;
  for (int s = 0; s < HORIZON; ++s) {
    const int rmask = (s == 0) ? 1023 : 0x7FFFFFFF;
    if (s == 0) {
      // [policy L1 | dyn L1z] only: M=1024 (shared latent), N=2048
      gemm128<<<dim3(8, 16), blk, 0, stream>>>(Zb0, 256, 256, pdW1vt, pdb1,
                                               1024, Ha, Hp, 1024);
      // policy L2 at M=1024
      gemm128<<<dim3(8, 8), blk, 0, stream>>>(Ha, 1024, 1024, pW2t, pb2, BIG,
                                              Hc, Hc, 1024);
    } else {
      // trunk + value-L1 for pragmatic(s-1) on z_s: N=3072, K=256
      gemm_pd1v<<<dim3(128, 24), blk, 0, stream>>>(
          Zb, pdW1vt, pdb1, vbias + (s - 1) * 1024, Ha, Hp, Hv);
      // fused {policy L2 -> Hc} then {value L2 + vW3 dot -> efe}, grid 256
      gemm256_dual<16><<<dim3(256), blk2, 0, stream>>>(
          Ha, pW2t, pb2, Hc, Hv, vW2t, vb2, vW3, efe, dprev);
    }
    // heads + dyn-L1 completion: Hc,Hp (masked rows) -> action/ent, Hd -> Ha
    heads4<<<dim3(MR / 16), blk, 0, stream>>>(Hc, pHt, pbm, pbs, noise, Hp,
                                              dW1at, Ha, efe, s, disc, rmask);
    // dynamics L2: Ha -> Hc (8-phase 256-tile)
    gemm256<16, 0><<<dim3(256), blk2, 0, stream>>>(Ha, dW2t, 4, db2, nullptr,
                                                   Hc, nullptr, 0.f);
    // dynamics L3 fused with z_next / KL partials; writes Zb = z_{s+1}
    gemm_dyn3<<<dim3(MR / 64, 2), blk, 0, stream>>>(
        Hc, dW3t, db3, Zf, Zb, snAll + (size_t)s * MR, scAll + (size_t)s * MR);
    dprev = disc;
    disc *= 0.99f;
  }

  kl_batch<<<dim3(MR / 256), blk, 0, stream>>>(sz0, snAll, scAll, efe);

  // final pragmatic(4) on z_5: value L1 (dbuf 2-phase, K=256) then L2+dot
  gemm128<<<dim3(128, 8), blk, 0, stream>>>(Zb, 256, 256, vW1t,
                                            vbias + 4 * 1024, BIG, Hv, Hv,
                                            1024);
  gemm256<16, 1><<<dim3(256), blk2, 0, stream>>>(Hv, vW2t, 4, vb2, vW3,
                                                 nullptr, efe, dprev);
  finalize<<<dim3(4), blk, 0, stream>>>(efe, vb3, (float*)d_out);
}